// Round 9
// baseline (664.598 us; speedup 1.0000x reference)
//
#include <hip/hip_runtime.h>
#include <hip/hip_bf16.h>

#define NNODES 50000
#define NEDGES 400000
#define NGRAPH 50

typedef __bf16 bf16_t;
typedef __bf16 bf16x4_t __attribute__((ext_vector_type(4)));
typedef __bf16 bf16x8_t __attribute__((ext_vector_type(8)));
typedef float f32x4_t __attribute__((ext_vector_type(4)));

// ---------------- CSR build ----------------

__global__ void count_kernel(const int* __restrict__ dst, int* __restrict__ cnt, int E) {
    int e = blockIdx.x * 256 + threadIdx.x;
    if (e < E) atomicAdd(&cnt[dst[e]], 1);
}

__global__ void dinv_kernel(const int* __restrict__ cnt, float* __restrict__ dinv, int N) {
    int i = blockIdx.x * 256 + threadIdx.x;
    if (i < N) dinv[i] = rsqrtf((float)cnt[i] + 1.0f);
}

// hierarchical scan: pass1 per-block inclusive scan + block sums
__global__ void scan_part(const int* __restrict__ cnt, int* __restrict__ bsum,
                          int* __restrict__ pre, int N) {
    __shared__ int sm[256];
    int t = threadIdx.x;
    int i = blockIdx.x * 256 + t;
    sm[t] = (i < N) ? cnt[i] : 0;
    __syncthreads();
    for (int off = 1; off < 256; off <<= 1) {
        int x = (t >= off) ? sm[t - off] : 0;
        __syncthreads();
        sm[t] += x;
        __syncthreads();
    }
    if (i < N) pre[i] = sm[t];
    if (t == 255) bsum[blockIdx.x] = sm[255];
}

// pass2: single block scans <=256 block sums (inclusive)
__global__ void scan_bsum(int* __restrict__ bsum, int nb) {
    __shared__ int sm[256];
    int t = threadIdx.x;
    sm[t] = (t < nb) ? bsum[t] : 0;
    __syncthreads();
    for (int off = 1; off < 256; off <<= 1) {
        int x = (t >= off) ? sm[t - off] : 0;
        __syncthreads();
        sm[t] += x;
        __syncthreads();
    }
    if (t < nb) bsum[t] = sm[t];
}

// pass3: row_ptr[i+1] = pre[i] + offset(block)
__global__ void scan_final(const int* __restrict__ pre, const int* __restrict__ bsum,
                           int* __restrict__ row_ptr, int N) {
    int i = blockIdx.x * 256 + threadIdx.x;
    if (i == 0) row_ptr[0] = 0;
    if (i < N) {
        int off = (blockIdx.x > 0) ? bsum[blockIdx.x - 1] : 0;
        row_ptr[i + 1] = off + pre[i];
    }
}

__global__ void fill_kernel(const int* __restrict__ src, const int* __restrict__ dst,
                            const int* __restrict__ row_ptr, int* __restrict__ fill,
                            const float* __restrict__ dinv,
                            int* __restrict__ col, float* __restrict__ ew, int E) {
    int e = blockIdx.x * 256 + threadIdx.x;
    if (e < E) {
        int s = src[e], d = dst[e];
        int pos = row_ptr[d] + atomicAdd(&fill[d], 1);
        col[pos] = s;
        ew[pos] = dinv[s] * dinv[d];
    }
}

// batch is SORTED: find graph start offsets with one coalesced pass, zero atomics.
__global__ void graph_starts(const int* __restrict__ batch, int* __restrict__ start, int N) {
    int i = blockIdx.x * 256 + threadIdx.x;
    if (i >= N) return;
    int b = batch[i];
    if (i == 0) {
        for (int g = 0; g <= b; ++g) start[g] = 0;
    } else {
        int p = batch[i - 1];
        for (int g = p + 1; g <= b; ++g) start[g] = i;
    }
    if (i == N - 1) {
        for (int g = b + 1; g <= NGRAPH; ++g) start[g] = N;
    }
}

// W5 prep: split into hi/lo bf16, transposed to [col][k] (B^T layout for MFMA frags)
__global__ void prep_w5(const float* __restrict__ W, bf16_t* __restrict__ hi,
                        bf16_t* __restrict__ lo) {
    int i = blockIdx.x * 256 + threadIdx.x;   // over 256*512
    if (i < 256 * 512) {
        int k = i / 512, c = i % 512;
        float v = W[i];
        bf16_t h = (bf16_t)v;
        float r = v - (float)h;
        hi[c * 256 + k] = h;
        lo[c * 256 + k] = (bf16_t)r;
    }
}

// ---------------- persistent dense transform: Y = [relu](X @ W [+ b]) ----------------

template <int CIN, int COUT, int RPT, bool PR, typename InT = float, typename OutT = float>
__global__ __launch_bounds__(256) void transform_persist(const InT* __restrict__ X,
                                                         const float* __restrict__ W,
                                                         const float* __restrict__ bias,
                                                         OutT* __restrict__ Y, int N) {
    constexpr int RT = RPT * COUT / 256;
    __shared__ float Ws[CIN * COUT];
    __shared__ float ps[RPT * CIN];
    int t = threadIdx.x;
    for (int i = t; i < CIN * COUT; i += 256) Ws[i] = W[i];

    int j = t % COUT;
    int lb = (t / COUT) * RT;
    float bv = 0.f;
    if constexpr (PR) bv = bias[j];

    int ntiles = (N + RPT - 1) / RPT;
    for (int tile = blockIdx.x; tile < ntiles; tile += gridDim.x) {
        int row0 = tile * RPT;
        __syncthreads();
        for (int i = t; i < RPT * CIN; i += 256) {
            int r = row0 + i / CIN;
            ps[i] = (r < N) ? (float)X[r * CIN + (i % CIN)] : 0.f;
        }
        __syncthreads();

        float acc[RT];
        #pragma unroll
        for (int r = 0; r < RT; ++r) acc[r] = bv;
        #pragma unroll
        for (int k = 0; k < CIN; ++k) {
            float w = Ws[k * COUT + j];
            #pragma unroll
            for (int r = 0; r < RT; ++r) acc[r] += ps[(lb + r) * CIN + k] * w;
        }
        #pragma unroll
        for (int r = 0; r < RT; ++r) {
            int row = row0 + lb + r;
            if (row < N) {
                float v = acc[r];
                if constexpr (PR) v = fmaxf(v, 0.f);
                Y[row * COUT + j] = (OutT)v;
            }
        }
    }
}

// ---------------- propagation (generic dtype): xout = Ahat xin [+bias, relu] ----------------

template <int C, bool PR, typename InT = float, typename OutT = float>
__global__ void propagate_kernel(const InT* __restrict__ xin, OutT* __restrict__ xout,
                                 const int* __restrict__ row_ptr, const int* __restrict__ col,
                                 const float* __restrict__ ew, const float* __restrict__ dinv,
                                 const float* __restrict__ bias, int N) {
    constexpr int NPB = 256 / C;
    int t = threadIdx.x;
    int node = blockIdx.x * NPB + t / C;
    int ch = t % C;
    if (node >= N) return;
    float di = dinv[node];
    float acc = (float)xin[node * C + ch] * di * di;
    int e0 = row_ptr[node], e1 = row_ptr[node + 1];
    for (int e = e0; e < e1; ++e) {
        acc += (float)xin[col[e] * C + ch] * ew[e];
    }
    if constexpr (PR) acc = fmaxf(acc + bias[ch], 0.f);
    xout[node * C + ch] = (OutT)acc;
}

// ---------------- propagation bf16, C=256: 1 node per wave, 4 ch/lane ----------------

__global__ __launch_bounds__(256) void propagate256_bf16(
    const bf16_t* __restrict__ xin, bf16_t* __restrict__ xout,
    const int* __restrict__ row_ptr, const int* __restrict__ col,
    const float* __restrict__ ew, const float* __restrict__ dinv, int N)
{
    int t = threadIdx.x;
    int node = blockIdx.x * 4 + (t >> 6);
    if (node >= N) return;
    int lane = t & 63;
    size_t base = (size_t)node * 256 + lane * 4;
    float di = dinv[node];
    float sn = di * di;
    bf16x4_t sv = *reinterpret_cast<const bf16x4_t*>(&xin[base]);
    float a0 = (float)sv[0] * sn, a1 = (float)sv[1] * sn;
    float a2 = (float)sv[2] * sn, a3 = (float)sv[3] * sn;
    int e0 = row_ptr[node], e1 = row_ptr[node + 1];
    for (int e = e0; e < e1; ++e) {
        int s = col[e];
        float w = ew[e];
        bf16x4_t v = *reinterpret_cast<const bf16x4_t*>(&xin[(size_t)s * 256 + lane * 4]);
        a0 += w * (float)v[0]; a1 += w * (float)v[1];
        a2 += w * (float)v[2]; a3 += w * (float)v[3];
    }
    bf16x4_t o;
    o[0] = (bf16_t)a0; o[1] = (bf16_t)a1; o[2] = (bf16_t)a2; o[3] = (bf16_t)a3;
    *reinterpret_cast<bf16x4_t*>(&xout[base]) = o;
}

// ---------------- L5: MFMA GEMM (N,256)x(256,512) bf16 + bias + relu + fused mean-pool ----
// One block per 128-row panel (grid 391), 8 waves (512 thr). A-panel staged ONCE in LDS
// (XOR-swizzled, 64 KB); block loops over 4 col-tiles of 128. W hi/lo streamed from L2.
// Wave (wr,wc): rows wr*32..+32, cols wc*64..+64 within col-tile. Pool into LDS red[512].

__global__ __launch_bounds__(512, 4) void gemm5_pool_mfma(
    const bf16_t* __restrict__ A, const bf16_t* __restrict__ Wth,
    const bf16_t* __restrict__ Wtl, const float* __restrict__ bias,
    const int* __restrict__ batch, float* __restrict__ out, int N)
{
    __shared__ bf16_t As[128 * 256];   // 64 KB, swizzled: elem(row,kq) at row*256 + ((kq^(row&7))*8)
    __shared__ float red[512];
    int t = threadIdx.x;
    int wave = t >> 6, lane = t & 63;
    int wr = wave >> 1, wc = wave & 1;
    int lr = lane & 15, kg = lane >> 4;
    int brow = blockIdx.x * 128;

    // stage A panel: 128 rows x 32 16B-units; 512 threads x 8 iters, coalesced global reads
    #pragma unroll
    for (int i = 0; i < 8; ++i) {
        int idx = i * 512 + t;
        int row = idx >> 5, kq = idx & 31;
        int gr = brow + row; if (gr > N - 1) gr = N - 1;
        bf16x8_t v = *reinterpret_cast<const bf16x8_t*>(&A[(size_t)gr * 256 + kq * 8]);
        *reinterpret_cast<bf16x8_t*>(&As[row * 256 + ((kq ^ (row & 7)) << 3)]) = v;
    }
    red[t] = 0.f;
    __syncthreads();

    int rlast = brow + 127; if (rlast > N - 1) rlast = N - 1;
    bool uniform = (batch[brow] == batch[rlast]);
    int r0l = wr * 32 + lr;        // local row of frag 0
    int r1l = r0l + 16;            // local row of frag 1

    for (int ct = 0; ct < 4; ++ct) {
        int colw = ct * 128 + wc * 64;
        f32x4_t acc[2][4];
        #pragma unroll
        for (int i = 0; i < 2; ++i)
            #pragma unroll
            for (int j = 0; j < 4; ++j) {
                f32x4_t z = {0.f, 0.f, 0.f, 0.f};
                acc[i][j] = z;
            }

        #pragma unroll
        for (int kc = 0; kc < 256; kc += 32) {
            int kq = (kc >> 3) + kg;
            bf16x8_t a0 = *reinterpret_cast<const bf16x8_t*>(&As[r0l * 256 + ((kq ^ (r0l & 7)) << 3)]);
            bf16x8_t a1 = *reinterpret_cast<const bf16x8_t*>(&As[r1l * 256 + ((kq ^ (r1l & 7)) << 3)]);
            #pragma unroll
            for (int cf = 0; cf < 4; ++cf) {
                size_t bo = (size_t)(colw + cf * 16 + lr) * 256 + kc + kg * 8;
                bf16x8_t bh = *reinterpret_cast<const bf16x8_t*>(&Wth[bo]);
                bf16x8_t bl = *reinterpret_cast<const bf16x8_t*>(&Wtl[bo]);
                acc[0][cf] = __builtin_amdgcn_mfma_f32_16x16x32_bf16(a0, bh, acc[0][cf], 0, 0, 0);
                acc[0][cf] = __builtin_amdgcn_mfma_f32_16x16x32_bf16(a0, bl, acc[0][cf], 0, 0, 0);
                acc[1][cf] = __builtin_amdgcn_mfma_f32_16x16x32_bf16(a1, bh, acc[1][cf], 0, 0, 0);
                acc[1][cf] = __builtin_amdgcn_mfma_f32_16x16x32_bf16(a1, bl, acc[1][cf], 0, 0, 0);
            }
        }

        // bias + relu. C/D layout: col = colw+cf*16+lr, row(local) = wr*32+rf*16+kg*4+g
        float v[2][4][4];
        #pragma unroll
        for (int cf = 0; cf < 4; ++cf) {
            float bv = bias[colw + cf * 16 + lr];
            #pragma unroll
            for (int rf = 0; rf < 2; ++rf)
                #pragma unroll
                for (int g = 0; g < 4; ++g)
                    v[rf][cf][g] = fmaxf(acc[rf][cf][g] + bv, 0.f);
        }

        if (uniform) {
            #pragma unroll
            for (int cf = 0; cf < 4; ++cf) {
                float s = 0.f;
                #pragma unroll
                for (int rf = 0; rf < 2; ++rf)
                    #pragma unroll
                    for (int g = 0; g < 4; ++g) {
                        int r = brow + wr * 32 + rf * 16 + kg * 4 + g;
                        s += (r < N) ? v[rf][cf][g] : 0.f;
                    }
                s += __shfl_xor(s, 16, 64);
                s += __shfl_xor(s, 32, 64);
                if (lane < 16) atomicAdd(&red[colw + cf * 16 + lr], s);
            }
        } else {
            #pragma unroll
            for (int rf = 0; rf < 2; ++rf)
                #pragma unroll
                for (int g = 0; g < 4; ++g) {
                    int r = brow + wr * 32 + rf * 16 + kg * 4 + g;
                    if (r < N) {
                        int bb = batch[r];
                        #pragma unroll
                        for (int cf = 0; cf < 4; ++cf)
                            atomicAdd(&out[(size_t)bb * 512 + colw + cf * 16 + lr], v[rf][cf][g]);
                    }
                }
        }
    }

    if (uniform) {
        __syncthreads();
        int b0 = batch[brow];
        atomicAdd(&out[(size_t)b0 * 512 + t], red[t]);
    }
}

__global__ void divide_kernel(float* __restrict__ out, const int* __restrict__ start, int total) {
    int i = blockIdx.x * 256 + threadIdx.x;
    if (i < total) {
        int g = i >> 9;
        float c = (float)(start[g + 1] - start[g]);
        out[i] /= fmaxf(c, 1.f);
    }
}

// ---------------- launch ----------------

extern "C" void kernel_launch(void* const* d_in, const int* in_sizes, int n_in,
                              void* d_out, int out_size, void* d_ws, size_t ws_size,
                              hipStream_t stream) {
    const float* x   = (const float*)d_in[0];
    const int* ei    = (const int*)d_in[1];
    const int* batch = (const int*)d_in[2];
    const float* W1 = (const float*)d_in[3];  const float* b1 = (const float*)d_in[4];
    const float* W2 = (const float*)d_in[5];  const float* b2 = (const float*)d_in[6];
    const float* W3 = (const float*)d_in[7];  const float* b3 = (const float*)d_in[8];
    const float* W4 = (const float*)d_in[9];  const float* b4 = (const float*)d_in[10];
    const float* W5 = (const float*)d_in[11]; const float* b5 = (const float*)d_in[12];
    float* out = (float*)d_out;

    const int N = NNODES, E = NEDGES;
    const int* src = ei;
    const int* dst = ei + E;

    char* ws = (char*)d_ws;
    size_t off = 0;
    auto alloc = [&](size_t bytes) {
        void* p = ws + off;
        off += (bytes + 255) & ~size_t(255);
        return p;
    };
    float* bufA   = (float*)alloc(sizeof(float) * size_t(N) * 256);
    float* bufB   = (float*)alloc(sizeof(float) * size_t(N) * 256);
    int* cnt      = (int*)alloc(sizeof(int) * N);
    int* fill     = (int*)alloc(sizeof(int) * N);
    int* row_ptr  = (int*)alloc(sizeof(int) * (N + 1));
    int* col      = (int*)alloc(sizeof(int) * E);
    float* ew     = (float*)alloc(sizeof(float) * E);
    float* dinv   = (float*)alloc(sizeof(float) * N);
    int* gstart   = (int*)alloc(sizeof(int) * (NGRAPH + 1));
    int* pre      = (int*)alloc(sizeof(int) * N);
    int* bsum     = (int*)alloc(sizeof(int) * 256);
    bf16_t* wt_hi = (bf16_t*)alloc(sizeof(bf16_t) * 512 * 256);
    bf16_t* wt_lo = (bf16_t*)alloc(sizeof(bf16_t) * 512 * 256);

    hipMemsetAsync(cnt, 0, sizeof(int) * N, stream);
    hipMemsetAsync(fill, 0, sizeof(int) * N, stream);
    hipMemsetAsync(out, 0, sizeof(float) * out_size, stream);

    count_kernel<<<(E + 255) / 256, 256, 0, stream>>>(dst, cnt, E);
    dinv_kernel<<<(N + 255) / 256, 256, 0, stream>>>(cnt, dinv, N);
    int nb = (N + 255) / 256;   // 196
    scan_part<<<nb, 256, 0, stream>>>(cnt, bsum, pre, N);
    scan_bsum<<<1, 256, 0, stream>>>(bsum, nb);
    scan_final<<<nb, 256, 0, stream>>>(pre, bsum, row_ptr, N);
    fill_kernel<<<(E + 255) / 256, 256, 0, stream>>>(src, dst, row_ptr, fill, dinv, col, ew, E);
    graph_starts<<<nb, 256, 0, stream>>>(batch, gstart, N);
    prep_w5<<<(256 * 512 + 255) / 256, 256, 0, stream>>>(W5, wt_hi, wt_lo);

    // L1: transform-first (32 -> 8), then propagate (+b1, relu)
    transform_persist<32, 8, 32, false><<<1024, 256, 0, stream>>>(x, W1, nullptr, bufA, N);
    propagate_kernel<8, true><<<(N + 31) / 32, 256, 0, stream>>>(bufA, bufB, row_ptr, col, ew, dinv, b1, N);

    // L2: propagate-first (8), then transform 8->16
    propagate_kernel<8, false><<<(N + 31) / 32, 256, 0, stream>>>(bufB, bufA, row_ptr, col, ew, dinv, nullptr, N);
    transform_persist<8, 16, 32, true><<<1024, 256, 0, stream>>>(bufA, W2, b2, bufB, N);

    // L3: propagate (16), transform 16->64 with bf16 output
    propagate_kernel<16, false><<<(N + 15) / 16, 256, 0, stream>>>(bufB, bufA, row_ptr, col, ew, dinv, nullptr, N);
    bf16_t* h3b = (bf16_t*)bufB;
    transform_persist<16, 64, 16, true, float, bf16_t><<<1024, 256, 0, stream>>>(bufA, W3, b3, h3b, N);

    // L4: propagate bf16 (64), transform 64->256 bf16->bf16
    bf16_t* h4a = (bf16_t*)bufA;
    propagate_kernel<64, false, bf16_t, bf16_t><<<(N + 3) / 4, 256, 0, stream>>>(h3b, h4a, row_ptr, col, ew, dinv, nullptr, N);
    bf16_t* h4b = (bf16_t*)bufB;
    transform_persist<64, 256, 8, true, bf16_t, bf16_t><<<512, 256, 0, stream>>>(h4a, W4, b4, h4b, N);

    // L5: propagate bf16 (256), then MFMA GEMM + bias + relu + fused mean-pool
    bf16_t* h5in = (bf16_t*)bufA;
    propagate256_bf16<<<(N + 3) / 4, 256, 0, stream>>>(h4b, h5in, row_ptr, col, ew, dinv, N);
    gemm5_pool_mfma<<<(N + 127) / 128, 512, 0, stream>>>(h5in, wt_hi, wt_lo, b5, batch, out, N);
    divide_kernel<<<(NGRAPH * 512 + 255) / 256, 256, 0, stream>>>(out, gstart, NGRAPH * 512);
}

// Round 10
// 617.863 us; speedup vs baseline: 1.0756x; 1.0756x over previous
//
#include <hip/hip_runtime.h>
#include <hip/hip_bf16.h>

#define NNODES 50000
#define NEDGES 400000
#define NGRAPH 50

typedef __bf16 bf16_t;
typedef __bf16 bf16x4_t __attribute__((ext_vector_type(4)));
typedef __bf16 bf16x8_t __attribute__((ext_vector_type(8)));
typedef float f32x4_t __attribute__((ext_vector_type(4)));

// ---------------- CSR build ----------------

__global__ void count_kernel(const int* __restrict__ dst, int* __restrict__ cnt, int E) {
    int e = blockIdx.x * 256 + threadIdx.x;
    if (e < E) atomicAdd(&cnt[dst[e]], 1);
}

__global__ void dinv_kernel(const int* __restrict__ cnt, float* __restrict__ dinv, int N) {
    int i = blockIdx.x * 256 + threadIdx.x;
    if (i < N) dinv[i] = rsqrtf((float)cnt[i] + 1.0f);
}

// hierarchical scan: pass1 per-block inclusive scan + block sums
__global__ void scan_part(const int* __restrict__ cnt, int* __restrict__ bsum,
                          int* __restrict__ pre, int N) {
    __shared__ int sm[256];
    int t = threadIdx.x;
    int i = blockIdx.x * 256 + t;
    sm[t] = (i < N) ? cnt[i] : 0;
    __syncthreads();
    for (int off = 1; off < 256; off <<= 1) {
        int x = (t >= off) ? sm[t - off] : 0;
        __syncthreads();
        sm[t] += x;
        __syncthreads();
    }
    if (i < N) pre[i] = sm[t];
    if (t == 255) bsum[blockIdx.x] = sm[255];
}

// pass2: single block scans <=256 block sums (inclusive)
__global__ void scan_bsum(int* __restrict__ bsum, int nb) {
    __shared__ int sm[256];
    int t = threadIdx.x;
    sm[t] = (t < nb) ? bsum[t] : 0;
    __syncthreads();
    for (int off = 1; off < 256; off <<= 1) {
        int x = (t >= off) ? sm[t - off] : 0;
        __syncthreads();
        sm[t] += x;
        __syncthreads();
    }
    if (t < nb) bsum[t] = sm[t];
}

// pass3: row_ptr[i+1] = pre[i] + offset(block)
__global__ void scan_final(const int* __restrict__ pre, const int* __restrict__ bsum,
                           int* __restrict__ row_ptr, int N) {
    int i = blockIdx.x * 256 + threadIdx.x;
    if (i == 0) row_ptr[0] = 0;
    if (i < N) {
        int off = (blockIdx.x > 0) ? bsum[blockIdx.x - 1] : 0;
        row_ptr[i + 1] = off + pre[i];
    }
}

__global__ void fill_kernel(const int* __restrict__ src, const int* __restrict__ dst,
                            const int* __restrict__ row_ptr, int* __restrict__ fill,
                            const float* __restrict__ dinv,
                            int* __restrict__ col, float* __restrict__ ew, int E) {
    int e = blockIdx.x * 256 + threadIdx.x;
    if (e < E) {
        int s = src[e], d = dst[e];
        int pos = row_ptr[d] + atomicAdd(&fill[d], 1);
        col[pos] = s;
        ew[pos] = dinv[s] * dinv[d];
    }
}

// batch is SORTED: find graph start offsets with one coalesced pass, zero atomics.
__global__ void graph_starts(const int* __restrict__ batch, int* __restrict__ start, int N) {
    int i = blockIdx.x * 256 + threadIdx.x;
    if (i >= N) return;
    int b = batch[i];
    if (i == 0) {
        for (int g = 0; g <= b; ++g) start[g] = 0;
    } else {
        int p = batch[i - 1];
        for (int g = p + 1; g <= b; ++g) start[g] = i;
    }
    if (i == N - 1) {
        for (int g = b + 1; g <= NGRAPH; ++g) start[g] = N;
    }
}

// W5 prep: split into hi/lo bf16, transposed to [col][k] (B^T layout for MFMA frags)
__global__ void prep_w5(const float* __restrict__ W, bf16_t* __restrict__ hi,
                        bf16_t* __restrict__ lo) {
    int i = blockIdx.x * 256 + threadIdx.x;   // over 256*512
    if (i < 256 * 512) {
        int k = i / 512, c = i % 512;
        float v = W[i];
        bf16_t h = (bf16_t)v;
        float r = v - (float)h;
        hi[c * 256 + k] = h;
        lo[c * 256 + k] = (bf16_t)r;
    }
}

// ---------------- persistent dense transform: Y = [relu](X @ W [+ b]) ----------------

template <int CIN, int COUT, int RPT, bool PR, typename InT = float, typename OutT = float>
__global__ __launch_bounds__(256) void transform_persist(const InT* __restrict__ X,
                                                         const float* __restrict__ W,
                                                         const float* __restrict__ bias,
                                                         OutT* __restrict__ Y, int N) {
    constexpr int RT = RPT * COUT / 256;
    __shared__ float Ws[CIN * COUT];
    __shared__ float ps[RPT * CIN];
    int t = threadIdx.x;
    for (int i = t; i < CIN * COUT; i += 256) Ws[i] = W[i];

    int j = t % COUT;
    int lb = (t / COUT) * RT;
    float bv = 0.f;
    if constexpr (PR) bv = bias[j];

    int ntiles = (N + RPT - 1) / RPT;
    for (int tile = blockIdx.x; tile < ntiles; tile += gridDim.x) {
        int row0 = tile * RPT;
        __syncthreads();
        for (int i = t; i < RPT * CIN; i += 256) {
            int r = row0 + i / CIN;
            ps[i] = (r < N) ? (float)X[r * CIN + (i % CIN)] : 0.f;
        }
        __syncthreads();

        float acc[RT];
        #pragma unroll
        for (int r = 0; r < RT; ++r) acc[r] = bv;
        #pragma unroll
        for (int k = 0; k < CIN; ++k) {
            float w = Ws[k * COUT + j];
            #pragma unroll
            for (int r = 0; r < RT; ++r) acc[r] += ps[(lb + r) * CIN + k] * w;
        }
        #pragma unroll
        for (int r = 0; r < RT; ++r) {
            int row = row0 + lb + r;
            if (row < N) {
                float v = acc[r];
                if constexpr (PR) v = fmaxf(v, 0.f);
                Y[row * COUT + j] = (OutT)v;
            }
        }
    }
}

// ---------------- propagation (generic dtype): xout = Ahat xin [+bias, relu] ----------------

template <int C, bool PR, typename InT = float, typename OutT = float>
__global__ void propagate_kernel(const InT* __restrict__ xin, OutT* __restrict__ xout,
                                 const int* __restrict__ row_ptr, const int* __restrict__ col,
                                 const float* __restrict__ ew, const float* __restrict__ dinv,
                                 const float* __restrict__ bias, int N) {
    constexpr int NPB = 256 / C;
    int t = threadIdx.x;
    int node = blockIdx.x * NPB + t / C;
    int ch = t % C;
    if (node >= N) return;
    float di = dinv[node];
    float acc = (float)xin[node * C + ch] * di * di;
    int e0 = row_ptr[node], e1 = row_ptr[node + 1];
    for (int e = e0; e < e1; ++e) {
        acc += (float)xin[col[e] * C + ch] * ew[e];
    }
    if constexpr (PR) acc = fmaxf(acc + bias[ch], 0.f);
    xout[node * C + ch] = (OutT)acc;
}

// ---------------- propagation bf16, C=256: 1 node per wave, 4 ch/lane ----------------

__global__ __launch_bounds__(256) void propagate256_bf16(
    const bf16_t* __restrict__ xin, bf16_t* __restrict__ xout,
    const int* __restrict__ row_ptr, const int* __restrict__ col,
    const float* __restrict__ ew, const float* __restrict__ dinv, int N)
{
    int t = threadIdx.x;
    int node = blockIdx.x * 4 + (t >> 6);
    if (node >= N) return;
    int lane = t & 63;
    size_t base = (size_t)node * 256 + lane * 4;
    float di = dinv[node];
    float sn = di * di;
    bf16x4_t sv = *reinterpret_cast<const bf16x4_t*>(&xin[base]);
    float a0 = (float)sv[0] * sn, a1 = (float)sv[1] * sn;
    float a2 = (float)sv[2] * sn, a3 = (float)sv[3] * sn;
    int e0 = row_ptr[node], e1 = row_ptr[node + 1];
    for (int e = e0; e < e1; ++e) {
        int s = col[e];
        float w = ew[e];
        bf16x4_t v = *reinterpret_cast<const bf16x4_t*>(&xin[(size_t)s * 256 + lane * 4]);
        a0 += w * (float)v[0]; a1 += w * (float)v[1];
        a2 += w * (float)v[2]; a3 += w * (float)v[3];
    }
    bf16x4_t o;
    o[0] = (bf16_t)a0; o[1] = (bf16_t)a1; o[2] = (bf16_t)a2; o[3] = (bf16_t)a3;
    *reinterpret_cast<bf16x4_t*>(&xout[base]) = o;
}

// ---------------- L5: MFMA GEMM (N,256)x(256,512) bf16 + bias + relu + fused mean-pool ----
// One block per 64-row panel (grid 782), 4 waves (256 thr). A staged ONCE in 32 KB LDS
// (XOR swizzle kq^(row&7)); ct-loop x4 covers all 512 cols, W hi/lo streamed (L2-resident).
// Wave (wr,wc) = 32 rows x 64 cols within ct col-tile of 128. NO epilogue temp array:
// bias/relu/pool folded per-cf straight from acc (round-9 spill post-mortem).

__global__ __launch_bounds__(256, 4) void gemm5_pool_mfma(
    const bf16_t* __restrict__ A, const bf16_t* __restrict__ Wth,
    const bf16_t* __restrict__ Wtl, const float* __restrict__ bias,
    const int* __restrict__ batch, float* __restrict__ out, int N)
{
    __shared__ bf16_t As[64 * 256];   // 32 KB
    __shared__ float red[512];
    int t = threadIdx.x;
    int wave = t >> 6, lane = t & 63;
    int wr = wave >> 1, wc = wave & 1;
    int lr = lane & 15, kg = lane >> 4;
    int brow = blockIdx.x * 64;

    // stage A panel: 64 rows x 32 16B-units; 256 threads x 8 iters, coalesced
    #pragma unroll
    for (int i = 0; i < 8; ++i) {
        int idx = i * 256 + t;
        int row = idx >> 5, kq = idx & 31;
        int gr = brow + row; if (gr > N - 1) gr = N - 1;
        bf16x8_t v = *reinterpret_cast<const bf16x8_t*>(&A[(size_t)gr * 256 + kq * 8]);
        *reinterpret_cast<bf16x8_t*>(&As[row * 256 + ((kq ^ (row & 7)) << 3)]) = v;
    }
    red[t] = 0.f;
    red[t + 256] = 0.f;
    __syncthreads();

    int rlast = brow + 63; if (rlast > N - 1) rlast = N - 1;
    bool uniform = (batch[brow] == batch[rlast]);
    int r0l = wr * 32 + lr;
    int r1l = r0l + 16;

    // per-lane output rows (8 of them) + their graph ids for the non-uniform path
    int bb[2][4];
    if (!uniform) {
        #pragma unroll
        for (int rf = 0; rf < 2; ++rf)
            #pragma unroll
            for (int g = 0; g < 4; ++g) {
                int r = brow + wr * 32 + rf * 16 + kg * 4 + g;
                bb[rf][g] = (r < N) ? batch[r] : -1;
            }
    }

    for (int ct = 0; ct < 4; ++ct) {
        int colw = ct * 128 + wc * 64;
        f32x4_t acc[2][4];
        #pragma unroll
        for (int i = 0; i < 2; ++i)
            #pragma unroll
            for (int j = 0; j < 4; ++j) {
                f32x4_t z = {0.f, 0.f, 0.f, 0.f};
                acc[i][j] = z;
            }

        #pragma unroll
        for (int kc = 0; kc < 256; kc += 32) {
            int kq = (kc >> 3) + kg;
            bf16x8_t a0 = *reinterpret_cast<const bf16x8_t*>(&As[r0l * 256 + ((kq ^ (r0l & 7)) << 3)]);
            bf16x8_t a1 = *reinterpret_cast<const bf16x8_t*>(&As[r1l * 256 + ((kq ^ (r1l & 7)) << 3)]);
            #pragma unroll
            for (int cf = 0; cf < 4; ++cf) {
                size_t bo = (size_t)(colw + cf * 16 + lr) * 256 + kc + kg * 8;
                bf16x8_t bh = *reinterpret_cast<const bf16x8_t*>(&Wth[bo]);
                bf16x8_t bl = *reinterpret_cast<const bf16x8_t*>(&Wtl[bo]);
                acc[0][cf] = __builtin_amdgcn_mfma_f32_16x16x32_bf16(a0, bh, acc[0][cf], 0, 0, 0);
                acc[0][cf] = __builtin_amdgcn_mfma_f32_16x16x32_bf16(a0, bl, acc[0][cf], 0, 0, 0);
                acc[1][cf] = __builtin_amdgcn_mfma_f32_16x16x32_bf16(a1, bh, acc[1][cf], 0, 0, 0);
                acc[1][cf] = __builtin_amdgcn_mfma_f32_16x16x32_bf16(a1, bl, acc[1][cf], 0, 0, 0);
            }
        }

        // epilogue per cf, straight from acc (no temp array).
        // C/D layout: col = colw+cf*16+lr, row(local) = wr*32+rf*16+kg*4+g
        #pragma unroll
        for (int cf = 0; cf < 4; ++cf) {
            float bv = bias[colw + cf * 16 + lr];
            if (uniform) {
                float s = 0.f;
                #pragma unroll
                for (int rf = 0; rf < 2; ++rf)
                    #pragma unroll
                    for (int g = 0; g < 4; ++g) {
                        int r = brow + wr * 32 + rf * 16 + kg * 4 + g;
                        float vv = fmaxf(acc[rf][cf][g] + bv, 0.f);
                        s += (r < N) ? vv : 0.f;
                    }
                s += __shfl_xor(s, 16, 64);
                s += __shfl_xor(s, 32, 64);
                if (lane < 16) atomicAdd(&red[colw + cf * 16 + lr], s);
            } else {
                #pragma unroll
                for (int rf = 0; rf < 2; ++rf)
                    #pragma unroll
                    for (int g = 0; g < 4; ++g) {
                        float vv = fmaxf(acc[rf][cf][g] + bv, 0.f);
                        if (bb[rf][g] >= 0)
                            atomicAdd(&out[(size_t)bb[rf][g] * 512 + colw + cf * 16 + lr], vv);
                    }
            }
        }
    }

    if (uniform) {
        __syncthreads();
        int b0 = batch[brow];
        atomicAdd(&out[(size_t)b0 * 512 + t], red[t]);
        atomicAdd(&out[(size_t)b0 * 512 + t + 256], red[t + 256]);
    }
}

__global__ void divide_kernel(float* __restrict__ out, const int* __restrict__ start, int total) {
    int i = blockIdx.x * 256 + threadIdx.x;
    if (i < total) {
        int g = i >> 9;
        float c = (float)(start[g + 1] - start[g]);
        out[i] /= fmaxf(c, 1.f);
    }
}

// ---------------- launch ----------------

extern "C" void kernel_launch(void* const* d_in, const int* in_sizes, int n_in,
                              void* d_out, int out_size, void* d_ws, size_t ws_size,
                              hipStream_t stream) {
    const float* x   = (const float*)d_in[0];
    const int* ei    = (const int*)d_in[1];
    const int* batch = (const int*)d_in[2];
    const float* W1 = (const float*)d_in[3];  const float* b1 = (const float*)d_in[4];
    const float* W2 = (const float*)d_in[5];  const float* b2 = (const float*)d_in[6];
    const float* W3 = (const float*)d_in[7];  const float* b3 = (const float*)d_in[8];
    const float* W4 = (const float*)d_in[9];  const float* b4 = (const float*)d_in[10];
    const float* W5 = (const float*)d_in[11]; const float* b5 = (const float*)d_in[12];
    float* out = (float*)d_out;

    const int N = NNODES, E = NEDGES;
    const int* src = ei;
    const int* dst = ei + E;

    char* ws = (char*)d_ws;
    size_t off = 0;
    auto alloc = [&](size_t bytes) {
        void* p = ws + off;
        off += (bytes + 255) & ~size_t(255);
        return p;
    };
    float* bufA   = (float*)alloc(sizeof(float) * size_t(N) * 256);
    float* bufB   = (float*)alloc(sizeof(float) * size_t(N) * 256);
    int* cnt      = (int*)alloc(sizeof(int) * N);
    int* fill     = (int*)alloc(sizeof(int) * N);
    int* row_ptr  = (int*)alloc(sizeof(int) * (N + 1));
    int* col      = (int*)alloc(sizeof(int) * E);
    float* ew     = (float*)alloc(sizeof(float) * E);
    float* dinv   = (float*)alloc(sizeof(float) * N);
    int* gstart   = (int*)alloc(sizeof(int) * (NGRAPH + 1));
    int* pre      = (int*)alloc(sizeof(int) * N);
    int* bsum     = (int*)alloc(sizeof(int) * 256);
    bf16_t* wt_hi = (bf16_t*)alloc(sizeof(bf16_t) * 512 * 256);
    bf16_t* wt_lo = (bf16_t*)alloc(sizeof(bf16_t) * 512 * 256);

    hipMemsetAsync(cnt, 0, sizeof(int) * N, stream);
    hipMemsetAsync(fill, 0, sizeof(int) * N, stream);
    hipMemsetAsync(out, 0, sizeof(float) * out_size, stream);

    count_kernel<<<(E + 255) / 256, 256, 0, stream>>>(dst, cnt, E);
    dinv_kernel<<<(N + 255) / 256, 256, 0, stream>>>(cnt, dinv, N);
    int nb = (N + 255) / 256;   // 196
    scan_part<<<nb, 256, 0, stream>>>(cnt, bsum, pre, N);
    scan_bsum<<<1, 256, 0, stream>>>(bsum, nb);
    scan_final<<<nb, 256, 0, stream>>>(pre, bsum, row_ptr, N);
    fill_kernel<<<(E + 255) / 256, 256, 0, stream>>>(src, dst, row_ptr, fill, dinv, col, ew, E);
    graph_starts<<<nb, 256, 0, stream>>>(batch, gstart, N);
    prep_w5<<<(256 * 512 + 255) / 256, 256, 0, stream>>>(W5, wt_hi, wt_lo);

    // L1: transform-first (32 -> 8), then propagate (+b1, relu)
    transform_persist<32, 8, 32, false><<<1024, 256, 0, stream>>>(x, W1, nullptr, bufA, N);
    propagate_kernel<8, true><<<(N + 31) / 32, 256, 0, stream>>>(bufA, bufB, row_ptr, col, ew, dinv, b1, N);

    // L2: propagate-first (8), then transform 8->16
    propagate_kernel<8, false><<<(N + 31) / 32, 256, 0, stream>>>(bufB, bufA, row_ptr, col, ew, dinv, nullptr, N);
    transform_persist<8, 16, 32, true><<<1024, 256, 0, stream>>>(bufA, W2, b2, bufB, N);

    // L3: propagate (16), transform 16->64 with bf16 output
    propagate_kernel<16, false><<<(N + 15) / 16, 256, 0, stream>>>(bufB, bufA, row_ptr, col, ew, dinv, nullptr, N);
    bf16_t* h3b = (bf16_t*)bufB;
    transform_persist<16, 64, 16, true, float, bf16_t><<<1024, 256, 0, stream>>>(bufA, W3, b3, h3b, N);

    // L4: propagate bf16 (64), transform 64->256 bf16->bf16
    bf16_t* h4a = (bf16_t*)bufA;
    propagate_kernel<64, false, bf16_t, bf16_t><<<(N + 3) / 4, 256, 0, stream>>>(h3b, h4a, row_ptr, col, ew, dinv, nullptr, N);
    bf16_t* h4b = (bf16_t*)bufB;
    transform_persist<64, 256, 8, true, bf16_t, bf16_t><<<512, 256, 0, stream>>>(h4a, W4, b4, h4b, N);

    // L5: propagate bf16 (256), then MFMA GEMM + bias + relu + fused mean-pool
    bf16_t* h5in = (bf16_t*)bufA;
    propagate256_bf16<<<(N + 3) / 4, 256, 0, stream>>>(h4b, h5in, row_ptr, col, ew, dinv, N);
    gemm5_pool_mfma<<<(N + 63) / 64, 256, 0, stream>>>(h5in, wt_hi, wt_lo, b5, batch, out, N);
    divide_kernel<<<(NGRAPH * 512 + 255) / 256, 256, 0, stream>>>(out, gstart, NGRAPH * 512);
}

// Round 11
// 495.782 us; speedup vs baseline: 1.3405x; 1.2462x over previous
//
#include <hip/hip_runtime.h>
#include <hip/hip_bf16.h>

#define NNODES 50000
#define NEDGES 400000
#define NGRAPH 50

typedef __bf16 bf16_t;
typedef __bf16 bf16x4_t __attribute__((ext_vector_type(4)));
typedef __bf16 bf16x8_t __attribute__((ext_vector_type(8)));
typedef float f32x4_t __attribute__((ext_vector_type(4)));

// ---------------- CSR build ----------------

__global__ void count_kernel(const int* __restrict__ dst, int* __restrict__ cnt, int E) {
    int e = blockIdx.x * 256 + threadIdx.x;
    if (e < E) atomicAdd(&cnt[dst[e]], 1);
}

__global__ void dinv_kernel(const int* __restrict__ cnt, float* __restrict__ dinv, int N) {
    int i = blockIdx.x * 256 + threadIdx.x;
    if (i < N) dinv[i] = rsqrtf((float)cnt[i] + 1.0f);
}

// hierarchical scan: pass1 per-block inclusive scan + block sums
__global__ void scan_part(const int* __restrict__ cnt, int* __restrict__ bsum,
                          int* __restrict__ pre, int N) {
    __shared__ int sm[256];
    int t = threadIdx.x;
    int i = blockIdx.x * 256 + t;
    sm[t] = (i < N) ? cnt[i] : 0;
    __syncthreads();
    for (int off = 1; off < 256; off <<= 1) {
        int x = (t >= off) ? sm[t - off] : 0;
        __syncthreads();
        sm[t] += x;
        __syncthreads();
    }
    if (i < N) pre[i] = sm[t];
    if (t == 255) bsum[blockIdx.x] = sm[255];
}

// pass2: single block scans <=256 block sums (inclusive)
__global__ void scan_bsum(int* __restrict__ bsum, int nb) {
    __shared__ int sm[256];
    int t = threadIdx.x;
    sm[t] = (t < nb) ? bsum[t] : 0;
    __syncthreads();
    for (int off = 1; off < 256; off <<= 1) {
        int x = (t >= off) ? sm[t - off] : 0;
        __syncthreads();
        sm[t] += x;
        __syncthreads();
    }
    if (t < nb) bsum[t] = sm[t];
}

// pass3: row_ptr[i+1] = pre[i] + offset(block)
__global__ void scan_final(const int* __restrict__ pre, const int* __restrict__ bsum,
                           int* __restrict__ row_ptr, int N) {
    int i = blockIdx.x * 256 + threadIdx.x;
    if (i == 0) row_ptr[0] = 0;
    if (i < N) {
        int off = (blockIdx.x > 0) ? bsum[blockIdx.x - 1] : 0;
        row_ptr[i + 1] = off + pre[i];
    }
}

__global__ void fill_kernel(const int* __restrict__ src, const int* __restrict__ dst,
                            const int* __restrict__ row_ptr, int* __restrict__ fill,
                            const float* __restrict__ dinv,
                            int* __restrict__ col, float* __restrict__ ew, int E) {
    int e = blockIdx.x * 256 + threadIdx.x;
    if (e < E) {
        int s = src[e], d = dst[e];
        int pos = row_ptr[d] + atomicAdd(&fill[d], 1);
        col[pos] = s;
        ew[pos] = dinv[s] * dinv[d];
    }
}

// batch is SORTED: find graph start offsets with one coalesced pass, zero atomics.
__global__ void graph_starts(const int* __restrict__ batch, int* __restrict__ start, int N) {
    int i = blockIdx.x * 256 + threadIdx.x;
    if (i >= N) return;
    int b = batch[i];
    if (i == 0) {
        for (int g = 0; g <= b; ++g) start[g] = 0;
    } else {
        int p = batch[i - 1];
        for (int g = p + 1; g <= b; ++g) start[g] = i;
    }
    if (i == N - 1) {
        for (int g = b + 1; g <= NGRAPH; ++g) start[g] = N;
    }
}

// W prep: split into hi/lo bf16, transposed to [col][k] (B^T layout for MFMA frags)
template <int K, int C>
__global__ void prep_w(const float* __restrict__ W, bf16_t* __restrict__ hi,
                       bf16_t* __restrict__ lo) {
    int i = blockIdx.x * 256 + threadIdx.x;   // over K*C
    if (i < K * C) {
        int k = i / C, c = i % C;
        float v = W[i];
        bf16_t h = (bf16_t)v;
        float r = v - (float)h;
        hi[c * K + k] = h;
        lo[c * K + k] = (bf16_t)r;
    }
}

// ---------------- persistent dense transform: Y = [relu](X @ W [+ b]) ----------------

template <int CIN, int COUT, int RPT, bool PR, typename InT = float, typename OutT = float>
__global__ __launch_bounds__(256) void transform_persist(const InT* __restrict__ X,
                                                         const float* __restrict__ W,
                                                         const float* __restrict__ bias,
                                                         OutT* __restrict__ Y, int N) {
    constexpr int RT = RPT * COUT / 256;
    __shared__ float Ws[CIN * COUT];
    __shared__ float ps[RPT * CIN];
    int t = threadIdx.x;
    for (int i = t; i < CIN * COUT; i += 256) Ws[i] = W[i];

    int j = t % COUT;
    int lb = (t / COUT) * RT;
    float bv = 0.f;
    if constexpr (PR) bv = bias[j];

    int ntiles = (N + RPT - 1) / RPT;
    for (int tile = blockIdx.x; tile < ntiles; tile += gridDim.x) {
        int row0 = tile * RPT;
        __syncthreads();
        for (int i = t; i < RPT * CIN; i += 256) {
            int r = row0 + i / CIN;
            ps[i] = (r < N) ? (float)X[r * CIN + (i % CIN)] : 0.f;
        }
        __syncthreads();

        float acc[RT];
        #pragma unroll
        for (int r = 0; r < RT; ++r) acc[r] = bv;
        #pragma unroll
        for (int k = 0; k < CIN; ++k) {
            float w = Ws[k * COUT + j];
            #pragma unroll
            for (int r = 0; r < RT; ++r) acc[r] += ps[(lb + r) * CIN + k] * w;
        }
        #pragma unroll
        for (int r = 0; r < RT; ++r) {
            int row = row0 + lb + r;
            if (row < N) {
                float v = acc[r];
                if constexpr (PR) v = fmaxf(v, 0.f);
                Y[row * COUT + j] = (OutT)v;
            }
        }
    }
}

// ---------------- propagation (generic dtype): xout = Ahat xin [+bias, relu] ----------------

template <int C, bool PR, typename InT = float, typename OutT = float>
__global__ void propagate_kernel(const InT* __restrict__ xin, OutT* __restrict__ xout,
                                 const int* __restrict__ row_ptr, const int* __restrict__ col,
                                 const float* __restrict__ ew, const float* __restrict__ dinv,
                                 const float* __restrict__ bias, int N) {
    constexpr int NPB = 256 / C;
    int t = threadIdx.x;
    int node = blockIdx.x * NPB + t / C;
    int ch = t % C;
    if (node >= N) return;
    float di = dinv[node];
    float acc = (float)xin[node * C + ch] * di * di;
    int e0 = row_ptr[node], e1 = row_ptr[node + 1];
    for (int e = e0; e < e1; ++e) {
        acc += (float)xin[col[e] * C + ch] * ew[e];
    }
    if constexpr (PR) acc = fmaxf(acc + bias[ch], 0.f);
    xout[node * C + ch] = (OutT)acc;
}

// ---------------- propagation bf16, C=256: 1 node per wave, 4 ch/lane ----------------

__global__ __launch_bounds__(256) void propagate256_bf16(
    const bf16_t* __restrict__ xin, bf16_t* __restrict__ xout,
    const int* __restrict__ row_ptr, const int* __restrict__ col,
    const float* __restrict__ ew, const float* __restrict__ dinv, int N)
{
    int t = threadIdx.x;
    int node = blockIdx.x * 4 + (t >> 6);
    if (node >= N) return;
    int lane = t & 63;
    size_t base = (size_t)node * 256 + lane * 4;
    float di = dinv[node];
    float sn = di * di;
    bf16x4_t sv = *reinterpret_cast<const bf16x4_t*>(&xin[base]);
    float a0 = (float)sv[0] * sn, a1 = (float)sv[1] * sn;
    float a2 = (float)sv[2] * sn, a3 = (float)sv[3] * sn;
    int e0 = row_ptr[node], e1 = row_ptr[node + 1];
    for (int e = e0; e < e1; ++e) {
        int s = col[e];
        float w = ew[e];
        bf16x4_t v = *reinterpret_cast<const bf16x4_t*>(&xin[(size_t)s * 256 + lane * 4]);
        a0 += w * (float)v[0]; a1 += w * (float)v[1];
        a2 += w * (float)v[2]; a3 += w * (float)v[3];
    }
    bf16x4_t o;
    o[0] = (bf16_t)a0; o[1] = (bf16_t)a1; o[2] = (bf16_t)a2; o[3] = (bf16_t)a3;
    *reinterpret_cast<bf16x4_t*>(&xout[base]) = o;
}

// ---------------- L4: MFMA GEMM (N,64)x(64,256) bf16 + bias + relu -> bf16 ----------------
// One block per 64-row panel, 4 waves. A staged in 8 KB LDS (XOR swizzle on 8 kq slots).
// W4t hi/lo [256][64] streamed (L2-resident, 64 KB total). Wave (wr,wc) = 32r x 64c,
// ct loop x2 over col-tiles of 128. Same fragment/microtile pattern as gemm5.

__global__ __launch_bounds__(256) void transform4_mfma(
    const bf16_t* __restrict__ A, const bf16_t* __restrict__ Wth,
    const bf16_t* __restrict__ Wtl, const float* __restrict__ bias,
    bf16_t* __restrict__ Y, int N)
{
    __shared__ bf16_t As[64 * 64];   // 8 KB, elem(row,kq) at row*64 + ((kq^(row&7))*8)
    int t = threadIdx.x;
    int wave = t >> 6, lane = t & 63;
    int wr = wave >> 1, wc = wave & 1;
    int lr = lane & 15, kg = lane >> 4;
    int brow = blockIdx.x * 64;

    // stage A: 64 rows x 8 16B-units; 512 units, 256 threads x 2 iters
    #pragma unroll
    for (int i = 0; i < 2; ++i) {
        int idx = i * 256 + t;
        int row = idx >> 3, kq = idx & 7;
        int gr = brow + row; if (gr > N - 1) gr = N - 1;
        bf16x8_t v = *reinterpret_cast<const bf16x8_t*>(&A[(size_t)gr * 64 + kq * 8]);
        *reinterpret_cast<bf16x8_t*>(&As[row * 64 + ((kq ^ (row & 7)) << 3)]) = v;
    }
    __syncthreads();

    int r0l = wr * 32 + lr;
    int r1l = r0l + 16;

    #pragma unroll
    for (int ct = 0; ct < 2; ++ct) {
        int colw = ct * 128 + wc * 64;
        f32x4_t acc[2][4];
        #pragma unroll
        for (int i = 0; i < 2; ++i)
            #pragma unroll
            for (int j = 0; j < 4; ++j) {
                f32x4_t z = {0.f, 0.f, 0.f, 0.f};
                acc[i][j] = z;
            }

        #pragma unroll
        for (int kc = 0; kc < 64; kc += 32) {
            int kq = (kc >> 3) + kg;
            bf16x8_t a0 = *reinterpret_cast<const bf16x8_t*>(&As[r0l * 64 + ((kq ^ (r0l & 7)) << 3)]);
            bf16x8_t a1 = *reinterpret_cast<const bf16x8_t*>(&As[r1l * 64 + ((kq ^ (r1l & 7)) << 3)]);
            #pragma unroll
            for (int cf = 0; cf < 4; ++cf) {
                size_t bo = (size_t)(colw + cf * 16 + lr) * 64 + kc + kg * 8;
                bf16x8_t bh = *reinterpret_cast<const bf16x8_t*>(&Wth[bo]);
                bf16x8_t bl = *reinterpret_cast<const bf16x8_t*>(&Wtl[bo]);
                acc[0][cf] = __builtin_amdgcn_mfma_f32_16x16x32_bf16(a0, bh, acc[0][cf], 0, 0, 0);
                acc[0][cf] = __builtin_amdgcn_mfma_f32_16x16x32_bf16(a0, bl, acc[0][cf], 0, 0, 0);
                acc[1][cf] = __builtin_amdgcn_mfma_f32_16x16x32_bf16(a1, bh, acc[1][cf], 0, 0, 0);
                acc[1][cf] = __builtin_amdgcn_mfma_f32_16x16x32_bf16(a1, bl, acc[1][cf], 0, 0, 0);
            }
        }

        // epilogue: bias+relu, bf16 store. col = colw+cf*16+lr, row = brow+wr*32+rf*16+kg*4+g
        #pragma unroll
        for (int cf = 0; cf < 4; ++cf) {
            float bv = bias[colw + cf * 16 + lr];
            #pragma unroll
            for (int rf = 0; rf < 2; ++rf)
                #pragma unroll
                for (int g = 0; g < 4; ++g) {
                    int r = brow + wr * 32 + rf * 16 + kg * 4 + g;
                    if (r < N)
                        Y[(size_t)r * 256 + colw + cf * 16 + lr] =
                            (bf16_t)fmaxf(acc[rf][cf][g] + bv, 0.f);
                }
        }
    }
}

// ---------------- L5: MFMA GEMM (N,256)x(256,512) bf16 + bias + relu + fused mean-pool ----
// One block per 64-row panel, 4 waves. A staged ONCE in 32 KB LDS (XOR swizzle);
// ct-loop x4 covers 512 cols, W hi/lo streamed (L2-resident). Plain __launch_bounds__(256):
// round-10 post-mortem showed the min-waves hint clamped VGPRs to 64 and spilled 94 MB.

__global__ __launch_bounds__(256) void gemm5_pool_mfma(
    const bf16_t* __restrict__ A, const bf16_t* __restrict__ Wth,
    const bf16_t* __restrict__ Wtl, const float* __restrict__ bias,
    const int* __restrict__ batch, float* __restrict__ out, int N)
{
    __shared__ bf16_t As[64 * 256];   // 32 KB
    __shared__ float red[512];
    int t = threadIdx.x;
    int wave = t >> 6, lane = t & 63;
    int wr = wave >> 1, wc = wave & 1;
    int lr = lane & 15, kg = lane >> 4;
    int brow = blockIdx.x * 64;

    #pragma unroll
    for (int i = 0; i < 8; ++i) {
        int idx = i * 256 + t;
        int row = idx >> 5, kq = idx & 31;
        int gr = brow + row; if (gr > N - 1) gr = N - 1;
        bf16x8_t v = *reinterpret_cast<const bf16x8_t*>(&A[(size_t)gr * 256 + kq * 8]);
        *reinterpret_cast<bf16x8_t*>(&As[row * 256 + ((kq ^ (row & 7)) << 3)]) = v;
    }
    red[t] = 0.f;
    red[t + 256] = 0.f;
    __syncthreads();

    int rlast = brow + 63; if (rlast > N - 1) rlast = N - 1;
    bool uniform = (batch[brow] == batch[rlast]);
    int r0l = wr * 32 + lr;
    int r1l = r0l + 16;

    int bb[2][4];
    if (!uniform) {
        #pragma unroll
        for (int rf = 0; rf < 2; ++rf)
            #pragma unroll
            for (int g = 0; g < 4; ++g) {
                int r = brow + wr * 32 + rf * 16 + kg * 4 + g;
                bb[rf][g] = (r < N) ? batch[r] : -1;
            }
    }

    for (int ct = 0; ct < 4; ++ct) {
        int colw = ct * 128 + wc * 64;
        f32x4_t acc[2][4];
        #pragma unroll
        for (int i = 0; i < 2; ++i)
            #pragma unroll
            for (int j = 0; j < 4; ++j) {
                f32x4_t z = {0.f, 0.f, 0.f, 0.f};
                acc[i][j] = z;
            }

        #pragma unroll
        for (int kc = 0; kc < 256; kc += 32) {
            int kq = (kc >> 3) + kg;
            bf16x8_t a0 = *reinterpret_cast<const bf16x8_t*>(&As[r0l * 256 + ((kq ^ (r0l & 7)) << 3)]);
            bf16x8_t a1 = *reinterpret_cast<const bf16x8_t*>(&As[r1l * 256 + ((kq ^ (r1l & 7)) << 3)]);
            #pragma unroll
            for (int cf = 0; cf < 4; ++cf) {
                size_t bo = (size_t)(colw + cf * 16 + lr) * 256 + kc + kg * 8;
                bf16x8_t bh = *reinterpret_cast<const bf16x8_t*>(&Wth[bo]);
                bf16x8_t bl = *reinterpret_cast<const bf16x8_t*>(&Wtl[bo]);
                acc[0][cf] = __builtin_amdgcn_mfma_f32_16x16x32_bf16(a0, bh, acc[0][cf], 0, 0, 0);
                acc[0][cf] = __builtin_amdgcn_mfma_f32_16x16x32_bf16(a0, bl, acc[0][cf], 0, 0, 0);
                acc[1][cf] = __builtin_amdgcn_mfma_f32_16x16x32_bf16(a1, bh, acc[1][cf], 0, 0, 0);
                acc[1][cf] = __builtin_amdgcn_mfma_f32_16x16x32_bf16(a1, bl, acc[1][cf], 0, 0, 0);
            }
        }

        #pragma unroll
        for (int cf = 0; cf < 4; ++cf) {
            float bv = bias[colw + cf * 16 + lr];
            if (uniform) {
                float s = 0.f;
                #pragma unroll
                for (int rf = 0; rf < 2; ++rf)
                    #pragma unroll
                    for (int g = 0; g < 4; ++g) {
                        int r = brow + wr * 32 + rf * 16 + kg * 4 + g;
                        float vv = fmaxf(acc[rf][cf][g] + bv, 0.f);
                        s += (r < N) ? vv : 0.f;
                    }
                s += __shfl_xor(s, 16, 64);
                s += __shfl_xor(s, 32, 64);
                if (lane < 16) atomicAdd(&red[colw + cf * 16 + lr], s);
            } else {
                #pragma unroll
                for (int rf = 0; rf < 2; ++rf)
                    #pragma unroll
                    for (int g = 0; g < 4; ++g) {
                        float vv = fmaxf(acc[rf][cf][g] + bv, 0.f);
                        if (bb[rf][g] >= 0)
                            atomicAdd(&out[(size_t)bb[rf][g] * 512 + colw + cf * 16 + lr], vv);
                    }
            }
        }
    }

    if (uniform) {
        __syncthreads();
        int b0 = batch[brow];
        atomicAdd(&out[(size_t)b0 * 512 + t], red[t]);
        atomicAdd(&out[(size_t)b0 * 512 + t + 256], red[t + 256]);
    }
}

__global__ void divide_kernel(float* __restrict__ out, const int* __restrict__ start, int total) {
    int i = blockIdx.x * 256 + threadIdx.x;
    if (i < total) {
        int g = i >> 9;
        float c = (float)(start[g + 1] - start[g]);
        out[i] /= fmaxf(c, 1.f);
    }
}

// ---------------- launch ----------------

extern "C" void kernel_launch(void* const* d_in, const int* in_sizes, int n_in,
                              void* d_out, int out_size, void* d_ws, size_t ws_size,
                              hipStream_t stream) {
    const float* x   = (const float*)d_in[0];
    const int* ei    = (const int*)d_in[1];
    const int* batch = (const int*)d_in[2];
    const float* W1 = (const float*)d_in[3];  const float* b1 = (const float*)d_in[4];
    const float* W2 = (const float*)d_in[5];  const float* b2 = (const float*)d_in[6];
    const float* W3 = (const float*)d_in[7];  const float* b3 = (const float*)d_in[8];
    const float* W4 = (const float*)d_in[9];  const float* b4 = (const float*)d_in[10];
    const float* W5 = (const float*)d_in[11]; const float* b5 = (const float*)d_in[12];
    float* out = (float*)d_out;

    const int N = NNODES, E = NEDGES;
    const int* src = ei;
    const int* dst = ei + E;

    char* ws = (char*)d_ws;
    size_t off = 0;
    auto alloc = [&](size_t bytes) {
        void* p = ws + off;
        off += (bytes + 255) & ~size_t(255);
        return p;
    };
    float* bufA   = (float*)alloc(sizeof(float) * size_t(N) * 256);
    float* bufB   = (float*)alloc(sizeof(float) * size_t(N) * 256);
    int* cnt      = (int*)alloc(sizeof(int) * N);
    int* fill     = (int*)alloc(sizeof(int) * N);
    int* row_ptr  = (int*)alloc(sizeof(int) * (N + 1));
    int* col      = (int*)alloc(sizeof(int) * E);
    float* ew     = (float*)alloc(sizeof(float) * E);
    float* dinv   = (float*)alloc(sizeof(float) * N);
    int* gstart   = (int*)alloc(sizeof(int) * (NGRAPH + 1));
    int* pre      = (int*)alloc(sizeof(int) * N);
    int* bsum     = (int*)alloc(sizeof(int) * 256);
    bf16_t* wt_hi = (bf16_t*)alloc(sizeof(bf16_t) * 512 * 256);
    bf16_t* wt_lo = (bf16_t*)alloc(sizeof(bf16_t) * 512 * 256);
    bf16_t* w4_hi = (bf16_t*)alloc(sizeof(bf16_t) * 256 * 64);
    bf16_t* w4_lo = (bf16_t*)alloc(sizeof(bf16_t) * 256 * 64);

    hipMemsetAsync(cnt, 0, sizeof(int) * N, stream);
    hipMemsetAsync(fill, 0, sizeof(int) * N, stream);
    hipMemsetAsync(out, 0, sizeof(float) * out_size, stream);

    count_kernel<<<(E + 255) / 256, 256, 0, stream>>>(dst, cnt, E);
    dinv_kernel<<<(N + 255) / 256, 256, 0, stream>>>(cnt, dinv, N);
    int nb = (N + 255) / 256;   // 196
    scan_part<<<nb, 256, 0, stream>>>(cnt, bsum, pre, N);
    scan_bsum<<<1, 256, 0, stream>>>(bsum, nb);
    scan_final<<<nb, 256, 0, stream>>>(pre, bsum, row_ptr, N);
    fill_kernel<<<(E + 255) / 256, 256, 0, stream>>>(src, dst, row_ptr, fill, dinv, col, ew, E);
    graph_starts<<<nb, 256, 0, stream>>>(batch, gstart, N);
    prep_w<256, 512><<<(256 * 512 + 255) / 256, 256, 0, stream>>>(W5, wt_hi, wt_lo);
    prep_w<64, 256><<<(64 * 256 + 255) / 256, 256, 0, stream>>>(W4, w4_hi, w4_lo);

    // L1: transform-first (32 -> 8), then propagate (+b1, relu)
    transform_persist<32, 8, 32, false><<<1024, 256, 0, stream>>>(x, W1, nullptr, bufA, N);
    propagate_kernel<8, true><<<(N + 31) / 32, 256, 0, stream>>>(bufA, bufB, row_ptr, col, ew, dinv, b1, N);

    // L2: propagate-first (8), then transform 8->16
    propagate_kernel<8, false><<<(N + 31) / 32, 256, 0, stream>>>(bufB, bufA, row_ptr, col, ew, dinv, nullptr, N);
    transform_persist<8, 16, 32, true><<<1024, 256, 0, stream>>>(bufA, W2, b2, bufB, N);

    // L3: propagate (16), transform 16->64 with bf16 output
    propagate_kernel<16, false><<<(N + 15) / 16, 256, 0, stream>>>(bufB, bufA, row_ptr, col, ew, dinv, nullptr, N);
    bf16_t* h3b = (bf16_t*)bufB;
    transform_persist<16, 64, 16, true, float, bf16_t><<<1024, 256, 0, stream>>>(bufA, W3, b3, h3b, N);

    // L4: propagate bf16 (64), then MFMA transform 64->256 bf16->bf16
    bf16_t* h4a = (bf16_t*)bufA;
    propagate_kernel<64, false, bf16_t, bf16_t><<<(N + 3) / 4, 256, 0, stream>>>(h3b, h4a, row_ptr, col, ew, dinv, nullptr, N);
    bf16_t* h4b = (bf16_t*)bufB;
    transform4_mfma<<<(N + 63) / 64, 256, 0, stream>>>(h4a, w4_hi, w4_lo, b4, h4b, N);

    // L5: propagate bf16 (256), then MFMA GEMM + bias + relu + fused mean-pool
    bf16_t* h5in = (bf16_t*)bufA;
    propagate256_bf16<<<(N + 3) / 4, 256, 0, stream>>>(h4b, h5in, row_ptr, col, ew, dinv, N);
    gemm5_pool_mfma<<<(N + 63) / 64, 256, 0, stream>>>(h5in, wt_hi, wt_lo, b5, batch, out, N);
    divide_kernel<<<(NGRAPH * 512 + 255) / 256, 256, 0, stream>>>(out, gstart, NGRAPH * 512);
}

// Round 12
// 417.847 us; speedup vs baseline: 1.5905x; 1.1865x over previous
//
#include <hip/hip_runtime.h>
#include <hip/hip_bf16.h>

#define NNODES 50000
#define NEDGES 400000
#define NGRAPH 50

typedef __bf16 bf16_t;
typedef __bf16 bf16x4_t __attribute__((ext_vector_type(4)));
typedef __bf16 bf16x8_t __attribute__((ext_vector_type(8)));
typedef float f32x4_t __attribute__((ext_vector_type(4)));

// ---------------- CSR build ----------------

__global__ void count_kernel(const int* __restrict__ dst, int* __restrict__ cnt, int E) {
    int e = blockIdx.x * 256 + threadIdx.x;
    if (e < E) atomicAdd(&cnt[dst[e]], 1);
}

__global__ void dinv_kernel(const int* __restrict__ cnt, float* __restrict__ dinv, int N) {
    int i = blockIdx.x * 256 + threadIdx.x;
    if (i < N) dinv[i] = rsqrtf((float)cnt[i] + 1.0f);
}

// hierarchical scan: pass1 per-block inclusive scan + block sums
__global__ void scan_part(const int* __restrict__ cnt, int* __restrict__ bsum,
                          int* __restrict__ pre, int N) {
    __shared__ int sm[256];
    int t = threadIdx.x;
    int i = blockIdx.x * 256 + t;
    sm[t] = (i < N) ? cnt[i] : 0;
    __syncthreads();
    for (int off = 1; off < 256; off <<= 1) {
        int x = (t >= off) ? sm[t - off] : 0;
        __syncthreads();
        sm[t] += x;
        __syncthreads();
    }
    if (i < N) pre[i] = sm[t];
    if (t == 255) bsum[blockIdx.x] = sm[255];
}

// pass2: single block scans <=256 block sums (inclusive)
__global__ void scan_bsum(int* __restrict__ bsum, int nb) {
    __shared__ int sm[256];
    int t = threadIdx.x;
    sm[t] = (t < nb) ? bsum[t] : 0;
    __syncthreads();
    for (int off = 1; off < 256; off <<= 1) {
        int x = (t >= off) ? sm[t - off] : 0;
        __syncthreads();
        sm[t] += x;
        __syncthreads();
    }
    if (t < nb) bsum[t] = sm[t];
}

// pass3: row_ptr[i+1] = pre[i] + offset(block)
__global__ void scan_final(const int* __restrict__ pre, const int* __restrict__ bsum,
                           int* __restrict__ row_ptr, int N) {
    int i = blockIdx.x * 256 + threadIdx.x;
    if (i == 0) row_ptr[0] = 0;
    if (i < N) {
        int off = (blockIdx.x > 0) ? bsum[blockIdx.x - 1] : 0;
        row_ptr[i + 1] = off + pre[i];
    }
}

__global__ void fill_kernel(const int* __restrict__ src, const int* __restrict__ dst,
                            const int* __restrict__ row_ptr, int* __restrict__ fill,
                            const float* __restrict__ dinv,
                            int* __restrict__ col, float* __restrict__ ew, int E) {
    int e = blockIdx.x * 256 + threadIdx.x;
    if (e < E) {
        int s = src[e], d = dst[e];
        int pos = row_ptr[d] + atomicAdd(&fill[d], 1);
        col[pos] = s;
        ew[pos] = dinv[s] * dinv[d];
    }
}

// batch is SORTED: find graph start offsets with one coalesced pass, zero atomics.
__global__ void graph_starts(const int* __restrict__ batch, int* __restrict__ start, int N) {
    int i = blockIdx.x * 256 + threadIdx.x;
    if (i >= N) return;
    int b = batch[i];
    if (i == 0) {
        for (int g = 0; g <= b; ++g) start[g] = 0;
    } else {
        int p = batch[i - 1];
        for (int g = p + 1; g <= b; ++g) start[g] = i;
    }
    if (i == N - 1) {
        for (int g = b + 1; g <= NGRAPH; ++g) start[g] = N;
    }
}

// W prep, FRAGMENT-MAJOR packed layout (round-11 post-mortem: [col][k] layout made
// every wave W-load a 16-line scattered transaction; this makes it one 1KB coalesced).
// packed[cb][kc8][lane][j]: k = kc8*32 + (lane>>4)*8 + j, col = cb*16 + (lane&15).
// hi/lo split for precision (W = hi + lo, each bf16).
template <int K, int C>
__global__ void prep_w_packed(const float* __restrict__ W, bf16_t* __restrict__ hi,
                              bf16_t* __restrict__ lo) {
    constexpr int KT = K / 32;
    int i = blockIdx.x * 256 + threadIdx.x;   // over K*C
    if (i < K * C) {
        int j = i & 7;
        int lane = (i >> 3) & 63;
        int rest = i >> 9;
        int kc8 = rest % KT;
        int cb = rest / KT;
        int k = kc8 * 32 + ((lane >> 4) << 3) + j;
        int c = cb * 16 + (lane & 15);
        float v = W[k * C + c];
        bf16_t h = (bf16_t)v;
        float r = v - (float)h;
        hi[i] = h;
        lo[i] = (bf16_t)r;
    }
}

// ---------------- persistent dense transform: Y = [relu](X @ W [+ b]) ----------------

template <int CIN, int COUT, int RPT, bool PR, typename InT = float, typename OutT = float>
__global__ __launch_bounds__(256) void transform_persist(const InT* __restrict__ X,
                                                         const float* __restrict__ W,
                                                         const float* __restrict__ bias,
                                                         OutT* __restrict__ Y, int N) {
    constexpr int RT = RPT * COUT / 256;
    __shared__ float Ws[CIN * COUT];
    __shared__ float ps[RPT * CIN];
    int t = threadIdx.x;
    for (int i = t; i < CIN * COUT; i += 256) Ws[i] = W[i];

    int j = t % COUT;
    int lb = (t / COUT) * RT;
    float bv = 0.f;
    if constexpr (PR) bv = bias[j];

    int ntiles = (N + RPT - 1) / RPT;
    for (int tile = blockIdx.x; tile < ntiles; tile += gridDim.x) {
        int row0 = tile * RPT;
        __syncthreads();
        for (int i = t; i < RPT * CIN; i += 256) {
            int r = row0 + i / CIN;
            ps[i] = (r < N) ? (float)X[r * CIN + (i % CIN)] : 0.f;
        }
        __syncthreads();

        float acc[RT];
        #pragma unroll
        for (int r = 0; r < RT; ++r) acc[r] = bv;
        #pragma unroll
        for (int k = 0; k < CIN; ++k) {
            float w = Ws[k * COUT + j];
            #pragma unroll
            for (int r = 0; r < RT; ++r) acc[r] += ps[(lb + r) * CIN + k] * w;
        }
        #pragma unroll
        for (int r = 0; r < RT; ++r) {
            int row = row0 + lb + r;
            if (row < N) {
                float v = acc[r];
                if constexpr (PR) v = fmaxf(v, 0.f);
                Y[row * COUT + j] = (OutT)v;
            }
        }
    }
}

// ---------------- propagation (generic dtype): xout = Ahat xin [+bias, relu] ----------------

template <int C, bool PR, typename InT = float, typename OutT = float>
__global__ void propagate_kernel(const InT* __restrict__ xin, OutT* __restrict__ xout,
                                 const int* __restrict__ row_ptr, const int* __restrict__ col,
                                 const float* __restrict__ ew, const float* __restrict__ dinv,
                                 const float* __restrict__ bias, int N) {
    constexpr int NPB = 256 / C;
    int t = threadIdx.x;
    int node = blockIdx.x * NPB + t / C;
    int ch = t % C;
    if (node >= N) return;
    float di = dinv[node];
    float acc = (float)xin[node * C + ch] * di * di;
    int e0 = row_ptr[node], e1 = row_ptr[node + 1];
    for (int e = e0; e < e1; ++e) {
        acc += (float)xin[col[e] * C + ch] * ew[e];
    }
    if constexpr (PR) acc = fmaxf(acc + bias[ch], 0.f);
    xout[node * C + ch] = (OutT)acc;
}

// ---------------- propagation bf16, C=256: 1 node per wave, 4 ch/lane ----------------

__global__ __launch_bounds__(256) void propagate256_bf16(
    const bf16_t* __restrict__ xin, bf16_t* __restrict__ xout,
    const int* __restrict__ row_ptr, const int* __restrict__ col,
    const float* __restrict__ ew, const float* __restrict__ dinv, int N)
{
    int t = threadIdx.x;
    int node = blockIdx.x * 4 + (t >> 6);
    if (node >= N) return;
    int lane = t & 63;
    size_t base = (size_t)node * 256 + lane * 4;
    float di = dinv[node];
    float sn = di * di;
    bf16x4_t sv = *reinterpret_cast<const bf16x4_t*>(&xin[base]);
    float a0 = (float)sv[0] * sn, a1 = (float)sv[1] * sn;
    float a2 = (float)sv[2] * sn, a3 = (float)sv[3] * sn;
    int e0 = row_ptr[node], e1 = row_ptr[node + 1];
    for (int e = e0; e < e1; ++e) {
        int s = col[e];
        float w = ew[e];
        bf16x4_t v = *reinterpret_cast<const bf16x4_t*>(&xin[(size_t)s * 256 + lane * 4]);
        a0 += w * (float)v[0]; a1 += w * (float)v[1];
        a2 += w * (float)v[2]; a3 += w * (float)v[3];
    }
    bf16x4_t o;
    o[0] = (bf16_t)a0; o[1] = (bf16_t)a1; o[2] = (bf16_t)a2; o[3] = (bf16_t)a3;
    *reinterpret_cast<bf16x4_t*>(&xout[base]) = o;
}

// ---------------- L4: MFMA GEMM (N,64)x(64,256) bf16 + bias + relu -> bf16 ----------------
// A staged in 8 KB LDS (XOR swizzle). W packed fragment-major: wave load = 1KB coalesced.

__global__ __launch_bounds__(256) void transform4_mfma(
    const bf16_t* __restrict__ A, const bf16_t* __restrict__ Wth,
    const bf16_t* __restrict__ Wtl, const float* __restrict__ bias,
    bf16_t* __restrict__ Y, int N)
{
    __shared__ bf16_t As[64 * 64];   // 8 KB, elem(row,kq) at row*64 + ((kq^(row&7))*8)
    int t = threadIdx.x;
    int wave = t >> 6, lane = t & 63;
    int wr = wave >> 1, wc = wave & 1;
    int lr = lane & 15, kg = lane >> 4;
    int brow = blockIdx.x * 64;

    #pragma unroll
    for (int i = 0; i < 2; ++i) {
        int idx = i * 256 + t;
        int row = idx >> 3, kq = idx & 7;
        int gr = brow + row; if (gr > N - 1) gr = N - 1;
        bf16x8_t v = *reinterpret_cast<const bf16x8_t*>(&A[(size_t)gr * 64 + kq * 8]);
        *reinterpret_cast<bf16x8_t*>(&As[row * 64 + ((kq ^ (row & 7)) << 3)]) = v;
    }
    __syncthreads();

    int r0l = wr * 32 + lr;
    int r1l = r0l + 16;

    #pragma unroll
    for (int ct = 0; ct < 2; ++ct) {
        int colw = ct * 128 + wc * 64;
        int cbbase = colw >> 4;          // ct*8 + wc*4
        f32x4_t acc[2][4];
        #pragma unroll
        for (int i = 0; i < 2; ++i)
            #pragma unroll
            for (int j = 0; j < 4; ++j) {
                f32x4_t z = {0.f, 0.f, 0.f, 0.f};
                acc[i][j] = z;
            }

        #pragma unroll
        for (int kc8 = 0; kc8 < 2; ++kc8) {
            int kq = kc8 * 4 + kg;
            bf16x8_t a0 = *reinterpret_cast<const bf16x8_t*>(&As[r0l * 64 + ((kq ^ (r0l & 7)) << 3)]);
            bf16x8_t a1 = *reinterpret_cast<const bf16x8_t*>(&As[r1l * 64 + ((kq ^ (r1l & 7)) << 3)]);
            #pragma unroll
            for (int cf = 0; cf < 4; ++cf) {
                int cb = cbbase + cf;
                size_t bo = (((size_t)(cb * 2 + kc8)) << 9) + (lane << 3);  // *64 lanes *8 elems
                bf16x8_t bh = *reinterpret_cast<const bf16x8_t*>(&Wth[bo]);
                bf16x8_t bl = *reinterpret_cast<const bf16x8_t*>(&Wtl[bo]);
                acc[0][cf] = __builtin_amdgcn_mfma_f32_16x16x32_bf16(a0, bh, acc[0][cf], 0, 0, 0);
                acc[0][cf] = __builtin_amdgcn_mfma_f32_16x16x32_bf16(a0, bl, acc[0][cf], 0, 0, 0);
                acc[1][cf] = __builtin_amdgcn_mfma_f32_16x16x32_bf16(a1, bh, acc[1][cf], 0, 0, 0);
                acc[1][cf] = __builtin_amdgcn_mfma_f32_16x16x32_bf16(a1, bl, acc[1][cf], 0, 0, 0);
            }
        }

        #pragma unroll
        for (int cf = 0; cf < 4; ++cf) {
            float bv = bias[colw + cf * 16 + lr];
            #pragma unroll
            for (int rf = 0; rf < 2; ++rf)
                #pragma unroll
                for (int g = 0; g < 4; ++g) {
                    int r = brow + wr * 32 + rf * 16 + kg * 4 + g;
                    if (r < N)
                        Y[(size_t)r * 256 + colw + cf * 16 + lr] =
                            (bf16_t)fmaxf(acc[rf][cf][g] + bv, 0.f);
                }
        }
    }
}

// ---------------- L5: MFMA GEMM (N,256)x(256,512) bf16 + bias + relu + fused mean-pool ----
// A staged ONCE in 32 KB LDS; W packed fragment-major (1KB coalesced wave loads).

__global__ __launch_bounds__(256) void gemm5_pool_mfma(
    const bf16_t* __restrict__ A, const bf16_t* __restrict__ Wth,
    const bf16_t* __restrict__ Wtl, const float* __restrict__ bias,
    const int* __restrict__ batch, float* __restrict__ out, int N)
{
    __shared__ bf16_t As[64 * 256];   // 32 KB
    __shared__ float red[512];
    int t = threadIdx.x;
    int wave = t >> 6, lane = t & 63;
    int wr = wave >> 1, wc = wave & 1;
    int lr = lane & 15, kg = lane >> 4;
    int brow = blockIdx.x * 64;

    #pragma unroll
    for (int i = 0; i < 8; ++i) {
        int idx = i * 256 + t;
        int row = idx >> 5, kq = idx & 31;
        int gr = brow + row; if (gr > N - 1) gr = N - 1;
        bf16x8_t v = *reinterpret_cast<const bf16x8_t*>(&A[(size_t)gr * 256 + kq * 8]);
        *reinterpret_cast<bf16x8_t*>(&As[row * 256 + ((kq ^ (row & 7)) << 3)]) = v;
    }
    red[t] = 0.f;
    red[t + 256] = 0.f;
    __syncthreads();

    int rlast = brow + 63; if (rlast > N - 1) rlast = N - 1;
    bool uniform = (batch[brow] == batch[rlast]);
    int r0l = wr * 32 + lr;
    int r1l = r0l + 16;

    int bb[2][4];
    if (!uniform) {
        #pragma unroll
        for (int rf = 0; rf < 2; ++rf)
            #pragma unroll
            for (int g = 0; g < 4; ++g) {
                int r = brow + wr * 32 + rf * 16 + kg * 4 + g;
                bb[rf][g] = (r < N) ? batch[r] : -1;
            }
    }

    for (int ct = 0; ct < 4; ++ct) {
        int colw = ct * 128 + wc * 64;
        int cbbase = colw >> 4;
        f32x4_t acc[2][4];
        #pragma unroll
        for (int i = 0; i < 2; ++i)
            #pragma unroll
            for (int j = 0; j < 4; ++j) {
                f32x4_t z = {0.f, 0.f, 0.f, 0.f};
                acc[i][j] = z;
            }

        #pragma unroll
        for (int kc8 = 0; kc8 < 8; ++kc8) {
            int kq = kc8 * 4 + kg;
            bf16x8_t a0 = *reinterpret_cast<const bf16x8_t*>(&As[r0l * 256 + ((kq ^ (r0l & 7)) << 3)]);
            bf16x8_t a1 = *reinterpret_cast<const bf16x8_t*>(&As[r1l * 256 + ((kq ^ (r1l & 7)) << 3)]);
            #pragma unroll
            for (int cf = 0; cf < 4; ++cf) {
                int cb = cbbase + cf;
                size_t bo = (((size_t)(cb * 8 + kc8)) << 9) + (lane << 3);
                bf16x8_t bh = *reinterpret_cast<const bf16x8_t*>(&Wth[bo]);
                bf16x8_t bl = *reinterpret_cast<const bf16x8_t*>(&Wtl[bo]);
                acc[0][cf] = __builtin_amdgcn_mfma_f32_16x16x32_bf16(a0, bh, acc[0][cf], 0, 0, 0);
                acc[0][cf] = __builtin_amdgcn_mfma_f32_16x16x32_bf16(a0, bl, acc[0][cf], 0, 0, 0);
                acc[1][cf] = __builtin_amdgcn_mfma_f32_16x16x32_bf16(a1, bh, acc[1][cf], 0, 0, 0);
                acc[1][cf] = __builtin_amdgcn_mfma_f32_16x16x32_bf16(a1, bl, acc[1][cf], 0, 0, 0);
            }
        }

        #pragma unroll
        for (int cf = 0; cf < 4; ++cf) {
            float bv = bias[colw + cf * 16 + lr];
            if (uniform) {
                float s = 0.f;
                #pragma unroll
                for (int rf = 0; rf < 2; ++rf)
                    #pragma unroll
                    for (int g = 0; g < 4; ++g) {
                        int r = brow + wr * 32 + rf * 16 + kg * 4 + g;
                        float vv = fmaxf(acc[rf][cf][g] + bv, 0.f);
                        s += (r < N) ? vv : 0.f;
                    }
                s += __shfl_xor(s, 16, 64);
                s += __shfl_xor(s, 32, 64);
                if (lane < 16) atomicAdd(&red[colw + cf * 16 + lr], s);
            } else {
                #pragma unroll
                for (int rf = 0; rf < 2; ++rf)
                    #pragma unroll
                    for (int g = 0; g < 4; ++g) {
                        float vv = fmaxf(acc[rf][cf][g] + bv, 0.f);
                        if (bb[rf][g] >= 0)
                            atomicAdd(&out[(size_t)bb[rf][g] * 512 + colw + cf * 16 + lr], vv);
                    }
            }
        }
    }

    if (uniform) {
        __syncthreads();
        int b0 = batch[brow];
        atomicAdd(&out[(size_t)b0 * 512 + t], red[t]);
        atomicAdd(&out[(size_t)b0 * 512 + t + 256], red[t + 256]);
    }
}

__global__ void divide_kernel(float* __restrict__ out, const int* __restrict__ start, int total) {
    int i = blockIdx.x * 256 + threadIdx.x;
    if (i < total) {
        int g = i >> 9;
        float c = (float)(start[g + 1] - start[g]);
        out[i] /= fmaxf(c, 1.f);
    }
}

// ---------------- launch ----------------

extern "C" void kernel_launch(void* const* d_in, const int* in_sizes, int n_in,
                              void* d_out, int out_size, void* d_ws, size_t ws_size,
                              hipStream_t stream) {
    const float* x   = (const float*)d_in[0];
    const int* ei    = (const int*)d_in[1];
    const int* batch = (const int*)d_in[2];
    const float* W1 = (const float*)d_in[3];  const float* b1 = (const float*)d_in[4];
    const float* W2 = (const float*)d_in[5];  const float* b2 = (const float*)d_in[6];
    const float* W3 = (const float*)d_in[7];  const float* b3 = (const float*)d_in[8];
    const float* W4 = (const float*)d_in[9];  const float* b4 = (const float*)d_in[10];
    const float* W5 = (const float*)d_in[11]; const float* b5 = (const float*)d_in[12];
    float* out = (float*)d_out;

    const int N = NNODES, E = NEDGES;
    const int* src = ei;
    const int* dst = ei + E;

    char* ws = (char*)d_ws;
    size_t off = 0;
    auto alloc = [&](size_t bytes) {
        void* p = ws + off;
        off += (bytes + 255) & ~size_t(255);
        return p;
    };
    float* bufA   = (float*)alloc(sizeof(float) * size_t(N) * 256);
    float* bufB   = (float*)alloc(sizeof(float) * size_t(N) * 256);
    int* cnt      = (int*)alloc(sizeof(int) * N);
    int* fill     = (int*)alloc(sizeof(int) * N);
    int* row_ptr  = (int*)alloc(sizeof(int) * (N + 1));
    int* col      = (int*)alloc(sizeof(int) * E);
    float* ew     = (float*)alloc(sizeof(float) * E);
    float* dinv   = (float*)alloc(sizeof(float) * N);
    int* gstart   = (int*)alloc(sizeof(int) * (NGRAPH + 1));
    int* pre      = (int*)alloc(sizeof(int) * N);
    int* bsum     = (int*)alloc(sizeof(int) * 256);
    bf16_t* wt_hi = (bf16_t*)alloc(sizeof(bf16_t) * 512 * 256);
    bf16_t* wt_lo = (bf16_t*)alloc(sizeof(bf16_t) * 512 * 256);
    bf16_t* w4_hi = (bf16_t*)alloc(sizeof(bf16_t) * 256 * 64);
    bf16_t* w4_lo = (bf16_t*)alloc(sizeof(bf16_t) * 256 * 64);

    hipMemsetAsync(cnt, 0, sizeof(int) * N, stream);
    hipMemsetAsync(fill, 0, sizeof(int) * N, stream);
    hipMemsetAsync(out, 0, sizeof(float) * out_size, stream);

    count_kernel<<<(E + 255) / 256, 256, 0, stream>>>(dst, cnt, E);
    dinv_kernel<<<(N + 255) / 256, 256, 0, stream>>>(cnt, dinv, N);
    int nb = (N + 255) / 256;   // 196
    scan_part<<<nb, 256, 0, stream>>>(cnt, bsum, pre, N);
    scan_bsum<<<1, 256, 0, stream>>>(bsum, nb);
    scan_final<<<nb, 256, 0, stream>>>(pre, bsum, row_ptr, N);
    fill_kernel<<<(E + 255) / 256, 256, 0, stream>>>(src, dst, row_ptr, fill, dinv, col, ew, E);
    graph_starts<<<nb, 256, 0, stream>>>(batch, gstart, N);
    prep_w_packed<256, 512><<<(256 * 512 + 255) / 256, 256, 0, stream>>>(W5, wt_hi, wt_lo);
    prep_w_packed<64, 256><<<(64 * 256 + 255) / 256, 256, 0, stream>>>(W4, w4_hi, w4_lo);

    // L1: transform-first (32 -> 8), then propagate (+b1, relu)
    transform_persist<32, 8, 32, false><<<1024, 256, 0, stream>>>(x, W1, nullptr, bufA, N);
    propagate_kernel<8, true><<<(N + 31) / 32, 256, 0, stream>>>(bufA, bufB, row_ptr, col, ew, dinv, b1, N);

    // L2: propagate-first (8), then transform 8->16
    propagate_kernel<8, false><<<(N + 31) / 32, 256, 0, stream>>>(bufB, bufA, row_ptr, col, ew, dinv, nullptr, N);
    transform_persist<8, 16, 32, true><<<1024, 256, 0, stream>>>(bufA, W2, b2, bufB, N);

    // L3: propagate (16), transform 16->64 with bf16 output
    propagate_kernel<16, false><<<(N + 15) / 16, 256, 0, stream>>>(bufB, bufA, row_ptr, col, ew, dinv, nullptr, N);
    bf16_t* h3b = (bf16_t*)bufB;
    transform_persist<16, 64, 16, true, float, bf16_t><<<1024, 256, 0, stream>>>(bufA, W3, b3, h3b, N);

    // L4: propagate bf16 (64), then MFMA transform 64->256 bf16->bf16
    bf16_t* h4a = (bf16_t*)bufA;
    propagate_kernel<64, false, bf16_t, bf16_t><<<(N + 3) / 4, 256, 0, stream>>>(h3b, h4a, row_ptr, col, ew, dinv, nullptr, N);
    bf16_t* h4b = (bf16_t*)bufB;
    transform4_mfma<<<(N + 63) / 64, 256, 0, stream>>>(h4a, w4_hi, w4_lo, b4, h4b, N);

    // L5: propagate bf16 (256), then MFMA GEMM + bias + relu + fused mean-pool
    bf16_t* h5in = (bf16_t*)bufA;
    propagate256_bf16<<<(N + 3) / 4, 256, 0, stream>>>(h4b, h5in, row_ptr, col, ew, dinv, N);
    gemm5_pool_mfma<<<(N + 63) / 64, 256, 0, stream>>>(h5in, wt_hi, wt_lo, b5, batch, out, N);
    divide_kernel<<<(NGRAPH * 512 + 255) / 256, 256, 0, stream>>>(out, gstart, NGRAPH * 512);
}

// Round 15
// 414.923 us; speedup vs baseline: 1.6017x; 1.0070x over previous
//
#include <hip/hip_runtime.h>
#include <hip/hip_bf16.h>

#define NNODES 50000
#define NEDGES 400000
#define NGRAPH 50

typedef __bf16 bf16_t;
typedef __bf16 bf16x4_t __attribute__((ext_vector_type(4)));
typedef __bf16 bf16x8_t __attribute__((ext_vector_type(8)));
typedef float f32x4_t __attribute__((ext_vector_type(4)));

// ---------------- CSR build ----------------

__global__ void count_kernel(const int* __restrict__ dst, int* __restrict__ cnt, int E) {
    int e = blockIdx.x * 256 + threadIdx.x;
    if (e < E) atomicAdd(&cnt[dst[e]], 1);
}

// hierarchical scan: pass1 per-block inclusive scan + block sums
__global__ void scan_part(const int* __restrict__ cnt, int* __restrict__ bsum,
                          int* __restrict__ pre, int N) {
    __shared__ int sm[256];
    int t = threadIdx.x;
    int i = blockIdx.x * 256 + t;
    sm[t] = (i < N) ? cnt[i] : 0;
    __syncthreads();
    for (int off = 1; off < 256; off <<= 1) {
        int x = (t >= off) ? sm[t - off] : 0;
        __syncthreads();
        sm[t] += x;
        __syncthreads();
    }
    if (i < N) pre[i] = sm[t];
    if (t == 255) bsum[blockIdx.x] = sm[255];
}

// pass2: single block scans <=256 block sums (inclusive)
__global__ void scan_bsum(int* __restrict__ bsum, int nb) {
    __shared__ int sm[256];
    int t = threadIdx.x;
    sm[t] = (t < nb) ? bsum[t] : 0;
    __syncthreads();
    for (int off = 1; off < 256; off <<= 1) {
        int x = (t >= off) ? sm[t - off] : 0;
        __syncthreads();
        sm[t] += x;
        __syncthreads();
    }
    if (t < nb) bsum[t] = sm[t];
}

// pass3: row_ptr[i+1] = pre[i] + offset(block); also dinv (folded, saves a launch)
__global__ void scan_final(const int* __restrict__ pre, const int* __restrict__ bsum,
                           const int* __restrict__ cnt,
                           int* __restrict__ row_ptr, float* __restrict__ dinv, int N) {
    int i = blockIdx.x * 256 + threadIdx.x;
    if (i == 0) row_ptr[0] = 0;
    if (i < N) {
        int off = (blockIdx.x > 0) ? bsum[blockIdx.x - 1] : 0;
        row_ptr[i + 1] = off + pre[i];
        dinv[i] = rsqrtf((float)cnt[i] + 1.0f);
    }
}

__global__ void fill_kernel(const int* __restrict__ src, const int* __restrict__ dst,
                            const int* __restrict__ row_ptr, int* __restrict__ fill,
                            const float* __restrict__ dinv,
                            int* __restrict__ col, float* __restrict__ ew, int E) {
    int e = blockIdx.x * 256 + threadIdx.x;
    if (e < E) {
        int s = src[e], d = dst[e];
        int pos = row_ptr[d] + atomicAdd(&fill[d], 1);
        col[pos] = s;
        ew[pos] = dinv[s] * dinv[d];
    }
}

// batch is SORTED: find graph start offsets with one coalesced pass, zero atomics.
__global__ void graph_starts(const int* __restrict__ batch, int* __restrict__ start, int N) {
    int i = blockIdx.x * 256 + threadIdx.x;
    if (i >= N) return;
    int b = batch[i];
    if (i == 0) {
        for (int g = 0; g <= b; ++g) start[g] = 0;
    } else {
        int p = batch[i - 1];
        for (int g = p + 1; g <= b; ++g) start[g] = i;
    }
    if (i == N - 1) {
        for (int g = b + 1; g <= NGRAPH; ++g) start[g] = N;
    }
}

// W prep, FRAGMENT-MAJOR packed layout: wave W-load = one 1KB coalesced transaction.
// packed[cb][kc8][lane][j]: k = kc8*32 + (lane>>4)*8 + j, col = cb*16 + (lane&15).
template <int K, int C>
__global__ void prep_w_packed(const float* __restrict__ W, bf16_t* __restrict__ hi,
                              bf16_t* __restrict__ lo) {
    constexpr int KT = K / 32;
    int i = blockIdx.x * 256 + threadIdx.x;   // over K*C
    if (i < K * C) {
        int j = i & 7;
        int lane = (i >> 3) & 63;
        int rest = i >> 9;
        int kc8 = rest % KT;
        int cb = rest / KT;
        int k = kc8 * 32 + ((lane >> 4) << 3) + j;
        int c = cb * 16 + (lane & 15);
        float v = W[k * C + c];
        bf16_t h = (bf16_t)v;
        float r = v - (float)h;
        hi[i] = h;
        lo[i] = (bf16_t)r;
    }
}

// ---------------- persistent dense transform: Y = [relu](X @ W [+ b]) ----------------

template <int CIN, int COUT, int RPT, bool PR, typename InT = float, typename OutT = float>
__global__ __launch_bounds__(256) void transform_persist(const InT* __restrict__ X,
                                                         const float* __restrict__ W,
                                                         const float* __restrict__ bias,
                                                         OutT* __restrict__ Y, int N) {
    constexpr int RT = RPT * COUT / 256;
    __shared__ float Ws[CIN * COUT];
    __shared__ float ps[RPT * CIN];
    int t = threadIdx.x;
    for (int i = t; i < CIN * COUT; i += 256) Ws[i] = W[i];

    int j = t % COUT;
    int lb = (t / COUT) * RT;
    float bv = 0.f;
    if constexpr (PR) bv = bias[j];

    int ntiles = (N + RPT - 1) / RPT;
    for (int tile = blockIdx.x; tile < ntiles; tile += gridDim.x) {
        int row0 = tile * RPT;
        __syncthreads();
        for (int i = t; i < RPT * CIN; i += 256) {
            int r = row0 + i / CIN;
            ps[i] = (r < N) ? (float)X[r * CIN + (i % CIN)] : 0.f;
        }
        __syncthreads();

        float acc[RT];
        #pragma unroll
        for (int r = 0; r < RT; ++r) acc[r] = bv;
        #pragma unroll
        for (int k = 0; k < CIN; ++k) {
            float w = Ws[k * COUT + j];
            #pragma unroll
            for (int r = 0; r < RT; ++r) acc[r] += ps[(lb + r) * CIN + k] * w;
        }
        #pragma unroll
        for (int r = 0; r < RT; ++r) {
            int row = row0 + lb + r;
            if (row < N) {
                float v = acc[r];
                if constexpr (PR) v = fmaxf(v, 0.f);
                Y[row * COUT + j] = (OutT)v;
            }
        }
    }
}

// ---------------- propagation (generic dtype): xout = Ahat xin [+bias, relu] ----------------

template <int C, bool PR, typename InT = float, typename OutT = float>
__global__ void propagate_kernel(const InT* __restrict__ xin, OutT* __restrict__ xout,
                                 const int* __restrict__ row_ptr, const int* __restrict__ col,
                                 const float* __restrict__ ew, const float* __restrict__ dinv,
                                 const float* __restrict__ bias, int N) {
    constexpr int NPB = 256 / C;
    int t = threadIdx.x;
    int node = blockIdx.x * NPB + t / C;
    int ch = t % C;
    if (node >= N) return;
    float di = dinv[node];
    float acc = (float)xin[node * C + ch] * di * di;
    int e0 = row_ptr[node], e1 = row_ptr[node + 1];
    for (int e = e0; e < e1; ++e) {
        acc += (float)xin[col[e] * C + ch] * ew[e];
    }
    if constexpr (PR) acc = fmaxf(acc + bias[ch], 0.f);
    xout[node * C + ch] = (OutT)acc;
}

// ---------------- propagation bf16, C=256: 1 node per wave, 4 ch/lane ----------------

__global__ __launch_bounds__(256) void propagate256_bf16(
    const bf16_t* __restrict__ xin, bf16_t* __restrict__ xout,
    const int* __restrict__ row_ptr, const int* __restrict__ col,
    const float* __restrict__ ew, const float* __restrict__ dinv, int N)
{
    int t = threadIdx.x;
    int node = blockIdx.x * 4 + (t >> 6);
    if (node >= N) return;
    int lane = t & 63;
    size_t base = (size_t)node * 256 + lane * 4;
    float di = dinv[node];
    float sn = di * di;
    bf16x4_t sv = *reinterpret_cast<const bf16x4_t*>(&xin[base]);
    float a0 = (float)sv[0] * sn, a1 = (float)sv[1] * sn;
    float a2 = (float)sv[2] * sn, a3 = (float)sv[3] * sn;
    int e0 = row_ptr[node], e1 = row_ptr[node + 1];
    for (int e = e0; e < e1; ++e) {
        int s = col[e];
        float w = ew[e];
        bf16x4_t v = *reinterpret_cast<const bf16x4_t*>(&xin[(size_t)s * 256 + lane * 4]);
        a0 += w * (float)v[0]; a1 += w * (float)v[1];
        a2 += w * (float)v[2]; a3 += w * (float)v[3];
    }
    bf16x4_t o;
    o[0] = (bf16_t)a0; o[1] = (bf16_t)a1; o[2] = (bf16_t)a2; o[3] = (bf16_t)a3;
    *reinterpret_cast<bf16x4_t*>(&xout[base]) = o;
}

// ---------------- L4: MFMA GEMM (N,64)x(64,256) bf16 + bias + relu -> bf16 ----------------
// Col-disjoint waves: wave owns 64 cols x all 64 rows (4 row-frags). W loaded once/block.

__global__ __launch_bounds__(256) void transform4_mfma(
    const bf16_t* __restrict__ A, const bf16_t* __restrict__ Wth,
    const bf16_t* __restrict__ Wtl, const float* __restrict__ bias,
    bf16_t* __restrict__ Y, int N)
{
    __shared__ bf16_t As[64 * 64];   // 8 KB, elem(row,kq) at row*64 + ((kq^(row&7))*8)
    int t = threadIdx.x;
    int wave = t >> 6, lane = t & 63;
    int lr = lane & 15, kg = lane >> 4;
    int brow = blockIdx.x * 64;

    #pragma unroll
    for (int i = 0; i < 2; ++i) {
        int idx = i * 256 + t;
        int row = idx >> 3, kq = idx & 7;
        int gr = brow + row; if (gr > N - 1) gr = N - 1;
        bf16x8_t v = *reinterpret_cast<const bf16x8_t*>(&A[(size_t)gr * 64 + kq * 8]);
        *reinterpret_cast<bf16x8_t*>(&As[row * 64 + ((kq ^ (row & 7)) << 3)]) = v;
    }
    __syncthreads();

    int colw = wave * 64;
    int cbbase = colw >> 4;
    f32x4_t acc[4][4];   // [rf][cf]
    #pragma unroll
    for (int i = 0; i < 4; ++i)
        #pragma unroll
        for (int j = 0; j < 4; ++j) {
            f32x4_t z = {0.f, 0.f, 0.f, 0.f};
            acc[i][j] = z;
        }

    #pragma unroll
    for (int kc8 = 0; kc8 < 2; ++kc8) {
        int kq = kc8 * 4 + kg;
        bf16x8_t a[4];
        #pragma unroll
        for (int rf = 0; rf < 4; ++rf) {
            int rl = rf * 16 + lr;
            a[rf] = *reinterpret_cast<const bf16x8_t*>(&As[rl * 64 + ((kq ^ (rl & 7)) << 3)]);
        }
        #pragma unroll
        for (int cf = 0; cf < 4; ++cf) {
            int cb = cbbase + cf;
            size_t bo = (((size_t)(cb * 2 + kc8)) << 9) + (lane << 3);
            bf16x8_t bh = *reinterpret_cast<const bf16x8_t*>(&Wth[bo]);
            bf16x8_t bl = *reinterpret_cast<const bf16x8_t*>(&Wtl[bo]);
            #pragma unroll
            for (int rf = 0; rf < 4; ++rf) {
                acc[rf][cf] = __builtin_amdgcn_mfma_f32_16x16x32_bf16(a[rf], bh, acc[rf][cf], 0, 0, 0);
                acc[rf][cf] = __builtin_amdgcn_mfma_f32_16x16x32_bf16(a[rf], bl, acc[rf][cf], 0, 0, 0);
            }
        }
    }

    #pragma unroll
    for (int cf = 0; cf < 4; ++cf) {
        float bv = bias[colw + cf * 16 + lr];
        #pragma unroll
        for (int rf = 0; rf < 4; ++rf)
            #pragma unroll
            for (int g = 0; g < 4; ++g) {
                int r = brow + rf * 16 + kg * 4 + g;
                if (r < N)
                    Y[(size_t)r * 256 + colw + cf * 16 + lr] =
                        (bf16_t)fmaxf(acc[rf][cf][g] + bv, 0.f);
            }
    }
}

// ---------------- L5: MFMA GEMM (N,256)x(256,512) bf16 + bias + relu + fused mean-pool ----
// Col-disjoint waves (round-12 post-mortem: row-split waves duplicated every W load).
// Wave owns 64 cols x all 64 rows; 2 ct iters cover 512 cols; W loaded ONCE per block.
// Pool: each red[] slot written exactly once by one wave -> plain store, no LDS atomics.

__global__ __launch_bounds__(256) void gemm5_pool_mfma(
    const bf16_t* __restrict__ A, const bf16_t* __restrict__ Wth,
    const bf16_t* __restrict__ Wtl, const float* __restrict__ bias,
    const int* __restrict__ batch, float* __restrict__ out, int N)
{
    __shared__ bf16_t As[64 * 256];   // 32 KB
    __shared__ float red[512];
    int t = threadIdx.x;
    int wave = t >> 6, lane = t & 63;
    int lr = lane & 15, kg = lane >> 4;
    int brow = blockIdx.x * 64;

    #pragma unroll
    for (int i = 0; i < 8; ++i) {
        int idx = i * 256 + t;
        int row = idx >> 5, kq = idx & 31;
        int gr = brow + row; if (gr > N - 1) gr = N - 1;
        bf16x8_t v = *reinterpret_cast<const bf16x8_t*>(&A[(size_t)gr * 256 + kq * 8]);
        *reinterpret_cast<bf16x8_t*>(&As[row * 256 + ((kq ^ (row & 7)) << 3)]) = v;
    }
    __syncthreads();

    int rlast = brow + 63; if (rlast > N - 1) rlast = N - 1;
    bool uniform = (batch[brow] == batch[rlast]);

    int bb[4][4];
    if (!uniform) {
        #pragma unroll
        for (int rf = 0; rf < 4; ++rf)
            #pragma unroll
            for (int g = 0; g < 4; ++g) {
                int r = brow + rf * 16 + kg * 4 + g;
                bb[rf][g] = (r < N) ? batch[r] : -1;
            }
    }

    #pragma unroll
    for (int ct = 0; ct < 2; ++ct) {
        int colw = ct * 256 + wave * 64;
        int cbbase = colw >> 4;
        f32x4_t acc[4][4];
        #pragma unroll
        for (int i = 0; i < 4; ++i)
            #pragma unroll
            for (int j = 0; j < 4; ++j) {
                f32x4_t z = {0.f, 0.f, 0.f, 0.f};
                acc[i][j] = z;
            }

        #pragma unroll
        for (int kc8 = 0; kc8 < 8; ++kc8) {
            int kq = kc8 * 4 + kg;
            bf16x8_t a[4];
            #pragma unroll
            for (int rf = 0; rf < 4; ++rf) {
                int rl = rf * 16 + lr;
                a[rf] = *reinterpret_cast<const bf16x8_t*>(&As[rl * 256 + ((kq ^ (rl & 7)) << 3)]);
            }
            #pragma unroll
            for (int cf = 0; cf < 4; ++cf) {
                int cb = cbbase + cf;
                size_t bo = (((size_t)(cb * 8 + kc8)) << 9) + (lane << 3);
                bf16x8_t bh = *reinterpret_cast<const bf16x8_t*>(&Wth[bo]);
                bf16x8_t bl = *reinterpret_cast<const bf16x8_t*>(&Wtl[bo]);
                #pragma unroll
                for (int rf = 0; rf < 4; ++rf) {
                    acc[rf][cf] = __builtin_amdgcn_mfma_f32_16x16x32_bf16(a[rf], bh, acc[rf][cf], 0, 0, 0);
                    acc[rf][cf] = __builtin_amdgcn_mfma_f32_16x16x32_bf16(a[rf], bl, acc[rf][cf], 0, 0, 0);
                }
            }
        }

        #pragma unroll
        for (int cf = 0; cf < 4; ++cf) {
            float bv = bias[colw + cf * 16 + lr];
            if (uniform) {
                float s = 0.f;
                #pragma unroll
                for (int rf = 0; rf < 4; ++rf)
                    #pragma unroll
                    for (int g = 0; g < 4; ++g) {
                        int r = brow + rf * 16 + kg * 4 + g;
                        float vv = fmaxf(acc[rf][cf][g] + bv, 0.f);
                        s += (r < N) ? vv : 0.f;
                    }
                s += __shfl_xor(s, 16, 64);
                s += __shfl_xor(s, 32, 64);
                if (lane < 16) red[colw + cf * 16 + lr] = s;   // unique slot: plain store
            } else {
                #pragma unroll
                for (int rf = 0; rf < 4; ++rf)
                    #pragma unroll
                    for (int g = 0; g < 4; ++g) {
                        float vv = fmaxf(acc[rf][cf][g] + bv, 0.f);
                        if (bb[rf][g] >= 0)
                            atomicAdd(&out[(size_t)bb[rf][g] * 512 + colw + cf * 16 + lr], vv);
                    }
            }
        }
    }

    if (uniform) {
        __syncthreads();
        int b0 = batch[brow];
        atomicAdd(&out[(size_t)b0 * 512 + t], red[t]);
        atomicAdd(&out[(size_t)b0 * 512 + t + 256], red[t + 256]);
    }
}

__global__ void divide_kernel(float* __restrict__ out, const int* __restrict__ start, int total) {
    int i = blockIdx.x * 256 + threadIdx.x;
    if (i < total) {
        int g = i >> 9;
        float c = (float)(start[g + 1] - start[g]);
        out[i] /= fmaxf(c, 1.f);
    }
}

// ---------------- launch ----------------

extern "C" void kernel_launch(void* const* d_in, const int* in_sizes, int n_in,
                              void* d_out, int out_size, void* d_ws, size_t ws_size,
                              hipStream_t stream) {
    const float* x   = (const float*)d_in[0];
    const int* ei    = (const int*)d_in[1];
    const int* batch = (const int*)d_in[2];
    const float* W1 = (const float*)d_in[3];  const float* b1 = (const float*)d_in[4];
    const float* W2 = (const float*)d_in[5];  const float* b2 = (const float*)d_in[6];
    const float* W3 = (const float*)d_in[7];  const float* b3 = (const float*)d_in[8];
    const float* W4 = (const float*)d_in[9];  const float* b4 = (const float*)d_in[10];
    const float* W5 = (const float*)d_in[11]; const float* b5 = (const float*)d_in[12];
    float* out = (float*)d_out;

    const int N = NNODES, E = NEDGES;
    const int* src = ei;
    const int* dst = ei + E;

    char* ws = (char*)d_ws;
    size_t off = 0;
    auto alloc = [&](size_t bytes) {
        void* p = ws + off;
        off += (bytes + 255) & ~size_t(255);
        return p;
    };
    float* bufA   = (float*)alloc(sizeof(float) * size_t(N) * 256);
    float* bufB   = (float*)alloc(sizeof(float) * size_t(N) * 256);
    int* cnt      = (int*)alloc(sizeof(int) * N);
    int* fill     = (int*)alloc(sizeof(int) * N);
    int* row_ptr  = (int*)alloc(sizeof(int) * (N + 1));
    int* col      = (int*)alloc(sizeof(int) * E);
    float* ew     = (float*)alloc(sizeof(float) * E);
    float* dinv   = (float*)alloc(sizeof(float) * N);
    int* gstart   = (int*)alloc(sizeof(int) * (NGRAPH + 1));
    int* pre      = (int*)alloc(sizeof(int) * N);
    int* bsum     = (int*)alloc(sizeof(int) * 256);
    bf16_t* wt_hi = (bf16_t*)alloc(sizeof(bf16_t) * 512 * 256);
    bf16_t* wt_lo = (bf16_t*)alloc(sizeof(bf16_t) * 512 * 256);
    bf16_t* w4_hi = (bf16_t*)alloc(sizeof(bf16_t) * 256 * 64);
    bf16_t* w4_lo = (bf16_t*)alloc(sizeof(bf16_t) * 256 * 64);

    hipMemsetAsync(cnt, 0, sizeof(int) * N, stream);
    hipMemsetAsync(fill, 0, sizeof(int) * N, stream);
    hipMemsetAsync(out, 0, sizeof(float) * out_size, stream);

    count_kernel<<<(E + 255) / 256, 256, 0, stream>>>(dst, cnt, E);
    int nb = (N + 255) / 256;   // 196
    scan_part<<<nb, 256, 0, stream>>>(cnt, bsum, pre, N);
    scan_bsum<<<1, 256, 0, stream>>>(bsum, nb);
    scan_final<<<nb, 256, 0, stream>>>(pre, bsum, cnt, row_ptr, dinv, N);
    fill_kernel<<<(E + 255) / 256, 256, 0, stream>>>(src, dst, row_ptr, fill, dinv, col, ew, E);
    graph_starts<<<nb, 256, 0, stream>>>(batch, gstart, N);
    prep_w_packed<256, 512><<<(256 * 512 + 255) / 256, 256, 0, stream>>>(W5, wt_hi, wt_lo);
    prep_w_packed<64, 256><<<(64 * 256 + 255) / 256, 256, 0, stream>>>(W4, w4_hi, w4_lo);

    // L1: transform-first (32 -> 8), then propagate (+b1, relu)
    transform_persist<32, 8, 32, false><<<1024, 256, 0, stream>>>(x, W1, nullptr, bufA, N);
    propagate_kernel<8, true><<<(N + 31) / 32, 256, 0, stream>>>(bufA, bufB, row_ptr, col, ew, dinv, b1, N);

    // L2: propagate-first (8), then transform 8->16
    propagate_kernel<8, false><<<(N + 31) / 32, 256, 0, stream>>>(bufB, bufA, row_ptr, col, ew, dinv, nullptr, N);
    transform_persist<8, 16, 32, true><<<1024, 256, 0, stream>>>(bufA, W2, b2, bufB, N);

    // L3: propagate (16), transform 16->64 with bf16 output
    propagate_kernel<16, false><<<(N + 15) / 16, 256, 0, stream>>>(bufB, bufA, row_ptr, col, ew, dinv, nullptr, N);
    bf16_t* h3b = (bf16_t*)bufB;
    transform_persist<16, 64, 16, true, float, bf16_t><<<1024, 256, 0, stream>>>(bufA, W3, b3, h3b, N);

    // L4: propagate bf16 (64), then MFMA transform 64->256 bf16->bf16
    bf16_t* h4a = (bf16_t*)bufA;
    propagate_kernel<64, false, bf16_t, bf16_t><<<(N + 3) / 4, 256, 0, stream>>>(h3b, h4a, row_ptr, col, ew, dinv, nullptr, N);
    bf16_t* h4b = (bf16_t*)bufB;
    transform4_mfma<<<(N + 63) / 64, 256, 0, stream>>>(h4a, w4_hi, w4_lo, b4, h4b, N);

    // L5: propagate bf16 (256), then MFMA GEMM + bias + relu + fused mean-pool
    bf16_t* h5in = (bf16_t*)bufA;
    propagate256_bf16<<<(N + 3) / 4, 256, 0, stream>>>(h4b, h5in, row_ptr, col, ew, dinv, N);
    gemm5_pool_mfma<<<(N + 63) / 64, 256, 0, stream>>>(h5in, wt_hi, wt_lo, b5, batch, out, N);
    divide_kernel<<<(NGRAPH * 512 + 255) / 256, 256, 0, stream>>>(out, gstart, NGRAPH * 512);
}

// Round 16
// 373.031 us; speedup vs baseline: 1.7816x; 1.1123x over previous
//
#include <hip/hip_runtime.h>
#include <hip/hip_bf16.h>

#define NNODES 50000
#define NEDGES 400000
#define NGRAPH 50

typedef __bf16 bf16_t;
typedef __bf16 bf16x4_t __attribute__((ext_vector_type(4)));
typedef __bf16 bf16x8_t __attribute__((ext_vector_type(8)));
typedef float f32x4_t __attribute__((ext_vector_type(4)));

// ---------------- CSR build ----------------

__global__ void count_kernel(const int* __restrict__ dst, int* __restrict__ cnt, int E) {
    int e = blockIdx.x * 256 + threadIdx.x;
    if (e < E) atomicAdd(&cnt[dst[e]], 1);
}

// hierarchical scan: pass1 per-block inclusive scan + block sums
__global__ void scan_part(const int* __restrict__ cnt, int* __restrict__ bsum,
                          int* __restrict__ pre, int N) {
    __shared__ int sm[256];
    int t = threadIdx.x;
    int i = blockIdx.x * 256 + t;
    sm[t] = (i < N) ? cnt[i] : 0;
    __syncthreads();
    for (int off = 1; off < 256; off <<= 1) {
        int x = (t >= off) ? sm[t - off] : 0;
        __syncthreads();
        sm[t] += x;
        __syncthreads();
    }
    if (i < N) pre[i] = sm[t];
    if (t == 255) bsum[blockIdx.x] = sm[255];
}

// pass2: single block scans <=256 block sums (inclusive)
__global__ void scan_bsum(int* __restrict__ bsum, int nb) {
    __shared__ int sm[256];
    int t = threadIdx.x;
    sm[t] = (t < nb) ? bsum[t] : 0;
    __syncthreads();
    for (int off = 1; off < 256; off <<= 1) {
        int x = (t >= off) ? sm[t - off] : 0;
        __syncthreads();
        sm[t] += x;
        __syncthreads();
    }
    if (t < nb) bsum[t] = sm[t];
}

// pass3: row_ptr[i+1] = pre[i] + offset(block); also dinv (folded, saves a launch)
__global__ void scan_final(const int* __restrict__ pre, const int* __restrict__ bsum,
                           const int* __restrict__ cnt,
                           int* __restrict__ row_ptr, float* __restrict__ dinv, int N) {
    int i = blockIdx.x * 256 + threadIdx.x;
    if (i == 0) row_ptr[0] = 0;
    if (i < N) {
        int off = (blockIdx.x > 0) ? bsum[blockIdx.x - 1] : 0;
        row_ptr[i + 1] = off + pre[i];
        dinv[i] = rsqrtf((float)cnt[i] + 1.0f);
    }
}

__global__ void fill_kernel(const int* __restrict__ src, const int* __restrict__ dst,
                            const int* __restrict__ row_ptr, int* __restrict__ fill,
                            const float* __restrict__ dinv,
                            int* __restrict__ col, float* __restrict__ ew, int E) {
    int e = blockIdx.x * 256 + threadIdx.x;
    if (e < E) {
        int s = src[e], d = dst[e];
        int pos = row_ptr[d] + atomicAdd(&fill[d], 1);
        col[pos] = s;
        ew[pos] = dinv[s] * dinv[d];
    }
}

// batch is SORTED: find graph start offsets with one coalesced pass, zero atomics.
__global__ void graph_starts(const int* __restrict__ batch, int* __restrict__ start, int N) {
    int i = blockIdx.x * 256 + threadIdx.x;
    if (i >= N) return;
    int b = batch[i];
    if (i == 0) {
        for (int g = 0; g <= b; ++g) start[g] = 0;
    } else {
        int p = batch[i - 1];
        for (int g = p + 1; g <= b; ++g) start[g] = i;
    }
    if (i == N - 1) {
        for (int g = b + 1; g <= NGRAPH; ++g) start[g] = N;
    }
}

// W prep, FRAGMENT-MAJOR packed layout: wave W-load = one 1KB coalesced transaction.
// packed[cb][kc8][lane][j]: k = kc8*32 + (lane>>4)*8 + j, col = cb*16 + (lane&15).
template <int K, int C>
__global__ void prep_w_packed(const float* __restrict__ W, bf16_t* __restrict__ hi,
                              bf16_t* __restrict__ lo) {
    constexpr int KT = K / 32;
    int i = blockIdx.x * 256 + threadIdx.x;   // over K*C
    if (i < K * C) {
        int j = i & 7;
        int lane = (i >> 3) & 63;
        int rest = i >> 9;
        int kc8 = rest % KT;
        int cb = rest / KT;
        int k = kc8 * 32 + ((lane >> 4) << 3) + j;
        int c = cb * 16 + (lane & 15);
        float v = W[k * C + c];
        bf16_t h = (bf16_t)v;
        float r = v - (float)h;
        hi[i] = h;
        lo[i] = (bf16_t)r;
    }
}

// ---------------- persistent dense transform: Y = [relu](X @ W [+ b]) ----------------

template <int CIN, int COUT, int RPT, bool PR, typename InT = float, typename OutT = float>
__global__ __launch_bounds__(256) void transform_persist(const InT* __restrict__ X,
                                                         const float* __restrict__ W,
                                                         const float* __restrict__ bias,
                                                         OutT* __restrict__ Y, int N) {
    constexpr int RT = RPT * COUT / 256;
    __shared__ float Ws[CIN * COUT];
    __shared__ float ps[RPT * CIN];
    int t = threadIdx.x;
    for (int i = t; i < CIN * COUT; i += 256) Ws[i] = W[i];

    int j = t % COUT;
    int lb = (t / COUT) * RT;
    float bv = 0.f;
    if constexpr (PR) bv = bias[j];

    int ntiles = (N + RPT - 1) / RPT;
    for (int tile = blockIdx.x; tile < ntiles; tile += gridDim.x) {
        int row0 = tile * RPT;
        __syncthreads();
        for (int i = t; i < RPT * CIN; i += 256) {
            int r = row0 + i / CIN;
            ps[i] = (r < N) ? (float)X[r * CIN + (i % CIN)] : 0.f;
        }
        __syncthreads();

        float acc[RT];
        #pragma unroll
        for (int r = 0; r < RT; ++r) acc[r] = bv;
        #pragma unroll
        for (int k = 0; k < CIN; ++k) {
            float w = Ws[k * COUT + j];
            #pragma unroll
            for (int r = 0; r < RT; ++r) acc[r] += ps[(lb + r) * CIN + k] * w;
        }
        #pragma unroll
        for (int r = 0; r < RT; ++r) {
            int row = row0 + lb + r;
            if (row < N) {
                float v = acc[r];
                if constexpr (PR) v = fmaxf(v, 0.f);
                Y[row * COUT + j] = (OutT)v;
            }
        }
    }
}

// ---------------- propagation (generic dtype), 4-way edge ILP ----------------
// round-15 post-mortem: deg~8 serial gather loop is latency-bound; 4 gathers in flight.

template <int C, bool PR, typename InT = float, typename OutT = float>
__global__ void propagate_kernel(const InT* __restrict__ xin, OutT* __restrict__ xout,
                                 const int* __restrict__ row_ptr, const int* __restrict__ col,
                                 const float* __restrict__ ew, const float* __restrict__ dinv,
                                 const float* __restrict__ bias, int N) {
    constexpr int NPB = 256 / C;
    int t = threadIdx.x;
    int node = blockIdx.x * NPB + t / C;
    int ch = t % C;
    if (node >= N) return;
    float di = dinv[node];
    float acc = (float)xin[node * C + ch] * di * di;
    int e0 = row_ptr[node], e1 = row_ptr[node + 1];
    int e = e0;
    for (; e + 4 <= e1; e += 4) {
        int s0 = col[e + 0], s1 = col[e + 1], s2 = col[e + 2], s3 = col[e + 3];
        float w0 = ew[e + 0], w1 = ew[e + 1], w2 = ew[e + 2], w3 = ew[e + 3];
        float v0 = (float)xin[(size_t)s0 * C + ch];
        float v1 = (float)xin[(size_t)s1 * C + ch];
        float v2 = (float)xin[(size_t)s2 * C + ch];
        float v3 = (float)xin[(size_t)s3 * C + ch];
        acc += v0 * w0 + v1 * w1 + v2 * w2 + v3 * w3;
    }
    for (; e < e1; ++e) {
        acc += (float)xin[(size_t)col[e] * C + ch] * ew[e];
    }
    if constexpr (PR) acc = fmaxf(acc + bias[ch], 0.f);
    xout[node * C + ch] = (OutT)acc;
}

// ---------------- propagation bf16, C=256: 1 node per wave, 4 ch/lane, 4-way edge ILP ----

__global__ __launch_bounds__(256) void propagate256_bf16(
    const bf16_t* __restrict__ xin, bf16_t* __restrict__ xout,
    const int* __restrict__ row_ptr, const int* __restrict__ col,
    const float* __restrict__ ew, const float* __restrict__ dinv, int N)
{
    int t = threadIdx.x;
    int node = blockIdx.x * 4 + (t >> 6);
    if (node >= N) return;
    int lane = t & 63;
    size_t co = lane * 4;
    size_t base = (size_t)node * 256 + co;
    float di = dinv[node];
    float sn = di * di;
    bf16x4_t sv = *reinterpret_cast<const bf16x4_t*>(&xin[base]);
    float a0 = (float)sv[0] * sn, a1 = (float)sv[1] * sn;
    float a2 = (float)sv[2] * sn, a3 = (float)sv[3] * sn;
    int e0 = row_ptr[node], e1 = row_ptr[node + 1];
    int e = e0;
    for (; e + 4 <= e1; e += 4) {
        int s0 = col[e + 0], s1 = col[e + 1], s2 = col[e + 2], s3 = col[e + 3];
        float w0 = ew[e + 0], w1 = ew[e + 1], w2 = ew[e + 2], w3 = ew[e + 3];
        bf16x4_t v0 = *reinterpret_cast<const bf16x4_t*>(&xin[(size_t)s0 * 256 + co]);
        bf16x4_t v1 = *reinterpret_cast<const bf16x4_t*>(&xin[(size_t)s1 * 256 + co]);
        bf16x4_t v2 = *reinterpret_cast<const bf16x4_t*>(&xin[(size_t)s2 * 256 + co]);
        bf16x4_t v3 = *reinterpret_cast<const bf16x4_t*>(&xin[(size_t)s3 * 256 + co]);
        a0 += w0 * (float)v0[0] + w1 * (float)v1[0] + w2 * (float)v2[0] + w3 * (float)v3[0];
        a1 += w0 * (float)v0[1] + w1 * (float)v1[1] + w2 * (float)v2[1] + w3 * (float)v3[1];
        a2 += w0 * (float)v0[2] + w1 * (float)v1[2] + w2 * (float)v2[2] + w3 * (float)v3[2];
        a3 += w0 * (float)v0[3] + w1 * (float)v1[3] + w2 * (float)v2[3] + w3 * (float)v3[3];
    }
    for (; e < e1; ++e) {
        int s = col[e];
        float w = ew[e];
        bf16x4_t v = *reinterpret_cast<const bf16x4_t*>(&xin[(size_t)s * 256 + co]);
        a0 += w * (float)v[0]; a1 += w * (float)v[1];
        a2 += w * (float)v[2]; a3 += w * (float)v[3];
    }
    bf16x4_t o;
    o[0] = (bf16_t)a0; o[1] = (bf16_t)a1; o[2] = (bf16_t)a2; o[3] = (bf16_t)a3;
    *reinterpret_cast<bf16x4_t*>(&xout[base]) = o;
}

// ---------------- L4: MFMA GEMM (N,64)x(64,256) bf16 + bias + relu -> bf16 ----------------
// Col-disjoint waves. LDS layout: ROTATION swizzle (round-15 post-mortem: XOR-8 gave
// 8-way read conflicts since bank depended only on kq; rotation (kq+row)&7 restores 2-way).

__global__ __launch_bounds__(256) void transform4_mfma(
    const bf16_t* __restrict__ A, const bf16_t* __restrict__ Wth,
    const bf16_t* __restrict__ Wtl, const float* __restrict__ bias,
    bf16_t* __restrict__ Y, int N)
{
    __shared__ bf16_t As[64 * 64];   // 8 KB, elem(row,kq) at row*64 + (((kq+row)&7)*8)
    int t = threadIdx.x;
    int wave = t >> 6, lane = t & 63;
    int lr = lane & 15, kg = lane >> 4;
    int brow = blockIdx.x * 64;

    #pragma unroll
    for (int i = 0; i < 2; ++i) {
        int idx = i * 256 + t;
        int row = idx >> 3, kq = idx & 7;
        int gr = brow + row; if (gr > N - 1) gr = N - 1;
        bf16x8_t v = *reinterpret_cast<const bf16x8_t*>(&A[(size_t)gr * 64 + kq * 8]);
        *reinterpret_cast<bf16x8_t*>(&As[row * 64 + (((kq + row) & 7) << 3)]) = v;
    }
    __syncthreads();

    int colw = wave * 64;
    int cbbase = colw >> 4;
    f32x4_t acc[4][4];   // [rf][cf]
    #pragma unroll
    for (int i = 0; i < 4; ++i)
        #pragma unroll
        for (int j = 0; j < 4; ++j) {
            f32x4_t z = {0.f, 0.f, 0.f, 0.f};
            acc[i][j] = z;
        }

    #pragma unroll
    for (int kc8 = 0; kc8 < 2; ++kc8) {
        int kq = kc8 * 4 + kg;
        bf16x8_t a[4];
        #pragma unroll
        for (int rf = 0; rf < 4; ++rf) {
            int rl = rf * 16 + lr;
            a[rf] = *reinterpret_cast<const bf16x8_t*>(&As[rl * 64 + (((kq + rl) & 7) << 3)]);
        }
        #pragma unroll
        for (int cf = 0; cf < 4; ++cf) {
            int cb = cbbase + cf;
            size_t bo = (((size_t)(cb * 2 + kc8)) << 9) + (lane << 3);
            bf16x8_t bh = *reinterpret_cast<const bf16x8_t*>(&Wth[bo]);
            bf16x8_t bl = *reinterpret_cast<const bf16x8_t*>(&Wtl[bo]);
            #pragma unroll
            for (int rf = 0; rf < 4; ++rf) {
                acc[rf][cf] = __builtin_amdgcn_mfma_f32_16x16x32_bf16(a[rf], bh, acc[rf][cf], 0, 0, 0);
                acc[rf][cf] = __builtin_amdgcn_mfma_f32_16x16x32_bf16(a[rf], bl, acc[rf][cf], 0, 0, 0);
            }
        }
    }

    #pragma unroll
    for (int cf = 0; cf < 4; ++cf) {
        float bv = bias[colw + cf * 16 + lr];
        #pragma unroll
        for (int rf = 0; rf < 4; ++rf)
            #pragma unroll
            for (int g = 0; g < 4; ++g) {
                int r = brow + rf * 16 + kg * 4 + g;
                if (r < N)
                    Y[(size_t)r * 256 + colw + cf * 16 + lr] =
                        (bf16_t)fmaxf(acc[rf][cf][g] + bv, 0.f);
            }
    }
}

// ---------------- L5: MFMA GEMM (N,256)x(256,512) bf16 + bias + relu + fused mean-pool ----
// Col-disjoint waves; W packed fragment-major; LDS rotation swizzle (kq+row)&31.

__global__ __launch_bounds__(256) void gemm5_pool_mfma(
    const bf16_t* __restrict__ A, const bf16_t* __restrict__ Wth,
    const bf16_t* __restrict__ Wtl, const float* __restrict__ bias,
    const int* __restrict__ batch, float* __restrict__ out, int N)
{
    __shared__ bf16_t As[64 * 256];   // 32 KB, elem(row,kq) at row*256 + (((kq+row)&31)*8)
    __shared__ float red[512];
    int t = threadIdx.x;
    int wave = t >> 6, lane = t & 63;
    int lr = lane & 15, kg = lane >> 4;
    int brow = blockIdx.x * 64;

    #pragma unroll
    for (int i = 0; i < 8; ++i) {
        int idx = i * 256 + t;
        int row = idx >> 5, kq = idx & 31;
        int gr = brow + row; if (gr > N - 1) gr = N - 1;
        bf16x8_t v = *reinterpret_cast<const bf16x8_t*>(&A[(size_t)gr * 256 + kq * 8]);
        *reinterpret_cast<bf16x8_t*>(&As[row * 256 + (((kq + row) & 31) << 3)]) = v;
    }
    __syncthreads();

    int rlast = brow + 63; if (rlast > N - 1) rlast = N - 1;
    bool uniform = (batch[brow] == batch[rlast]);

    int bb[4][4];
    if (!uniform) {
        #pragma unroll
        for (int rf = 0; rf < 4; ++rf)
            #pragma unroll
            for (int g = 0; g < 4; ++g) {
                int r = brow + rf * 16 + kg * 4 + g;
                bb[rf][g] = (r < N) ? batch[r] : -1;
            }
    }

    #pragma unroll
    for (int ct = 0; ct < 2; ++ct) {
        int colw = ct * 256 + wave * 64;
        int cbbase = colw >> 4;
        f32x4_t acc[4][4];
        #pragma unroll
        for (int i = 0; i < 4; ++i)
            #pragma unroll
            for (int j = 0; j < 4; ++j) {
                f32x4_t z = {0.f, 0.f, 0.f, 0.f};
                acc[i][j] = z;
            }

        #pragma unroll
        for (int kc8 = 0; kc8 < 8; ++kc8) {
            int kq = kc8 * 4 + kg;
            bf16x8_t a[4];
            #pragma unroll
            for (int rf = 0; rf < 4; ++rf) {
                int rl = rf * 16 + lr;
                a[rf] = *reinterpret_cast<const bf16x8_t*>(&As[rl * 256 + (((kq + rl) & 31) << 3)]);
            }
            #pragma unroll
            for (int cf = 0; cf < 4; ++cf) {
                int cb = cbbase + cf;
                size_t bo = (((size_t)(cb * 8 + kc8)) << 9) + (lane << 3);
                bf16x8_t bh = *reinterpret_cast<const bf16x8_t*>(&Wth[bo]);
                bf16x8_t bl = *reinterpret_cast<const bf16x8_t*>(&Wtl[bo]);
                #pragma unroll
                for (int rf = 0; rf < 4; ++rf) {
                    acc[rf][cf] = __builtin_amdgcn_mfma_f32_16x16x32_bf16(a[rf], bh, acc[rf][cf], 0, 0, 0);
                    acc[rf][cf] = __builtin_amdgcn_mfma_f32_16x16x32_bf16(a[rf], bl, acc[rf][cf], 0, 0, 0);
                }
            }
        }

        #pragma unroll
        for (int cf = 0; cf < 4; ++cf) {
            float bv = bias[colw + cf * 16 + lr];
            if (uniform) {
                float s = 0.f;
                #pragma unroll
                for (int rf = 0; rf < 4; ++rf)
                    #pragma unroll
                    for (int g = 0; g < 4; ++g) {
                        int r = brow + rf * 16 + kg * 4 + g;
                        float vv = fmaxf(acc[rf][cf][g] + bv, 0.f);
                        s += (r < N) ? vv : 0.f;
                    }
                s += __shfl_xor(s, 16, 64);
                s += __shfl_xor(s, 32, 64);
                if (lane < 16) red[colw + cf * 16 + lr] = s;   // unique slot: plain store
            } else {
                #pragma unroll
                for (int rf = 0; rf < 4; ++rf)
                    #pragma unroll
                    for (int g = 0; g < 4; ++g) {
                        float vv = fmaxf(acc[rf][cf][g] + bv, 0.f);
                        if (bb[rf][g] >= 0)
                            atomicAdd(&out[(size_t)bb[rf][g] * 512 + colw + cf * 16 + lr], vv);
                    }
            }
        }
    }

    if (uniform) {
        __syncthreads();
        int b0 = batch[brow];
        atomicAdd(&out[(size_t)b0 * 512 + t], red[t]);
        atomicAdd(&out[(size_t)b0 * 512 + t + 256], red[t + 256]);
    }
}

__global__ void divide_kernel(float* __restrict__ out, const int* __restrict__ start, int total) {
    int i = blockIdx.x * 256 + threadIdx.x;
    if (i < total) {
        int g = i >> 9;
        float c = (float)(start[g + 1] - start[g]);
        out[i] /= fmaxf(c, 1.f);
    }
}

// ---------------- launch ----------------

extern "C" void kernel_launch(void* const* d_in, const int* in_sizes, int n_in,
                              void* d_out, int out_size, void* d_ws, size_t ws_size,
                              hipStream_t stream) {
    const float* x   = (const float*)d_in[0];
    const int* ei    = (const int*)d_in[1];
    const int* batch = (const int*)d_in[2];
    const float* W1 = (const float*)d_in[3];  const float* b1 = (const float*)d_in[4];
    const float* W2 = (const float*)d_in[5];  const float* b2 = (const float*)d_in[6];
    const float* W3 = (const float*)d_in[7];  const float* b3 = (const float*)d_in[8];
    const float* W4 = (const float*)d_in[9];  const float* b4 = (const float*)d_in[10];
    const float* W5 = (const float*)d_in[11]; const float* b5 = (const float*)d_in[12];
    float* out = (float*)d_out;

    const int N = NNODES, E = NEDGES;
    const int* src = ei;
    const int* dst = ei + E;

    char* ws = (char*)d_ws;
    size_t off = 0;
    auto alloc = [&](size_t bytes) {
        void* p = ws + off;
        off += (bytes + 255) & ~size_t(255);
        return p;
    };
    float* bufA   = (float*)alloc(sizeof(float) * size_t(N) * 256);
    float* bufB   = (float*)alloc(sizeof(float) * size_t(N) * 256);
    int* cnt      = (int*)alloc(sizeof(int) * N);
    int* fill     = (int*)alloc(sizeof(int) * N);
    int* row_ptr  = (int*)alloc(sizeof(int) * (N + 1));
    int* col      = (int*)alloc(sizeof(int) * E);
    float* ew     = (float*)alloc(sizeof(float) * E);
    float* dinv   = (float*)alloc(sizeof(float) * N);
    int* gstart   = (int*)alloc(sizeof(int) * (NGRAPH + 1));
    int* pre      = (int*)alloc(sizeof(int) * N);
    int* bsum     = (int*)alloc(sizeof(int) * 256);
    bf16_t* wt_hi = (bf16_t*)alloc(sizeof(bf16_t) * 512 * 256);
    bf16_t* wt_lo = (bf16_t*)alloc(sizeof(bf16_t) * 512 * 256);
    bf16_t* w4_hi = (bf16_t*)alloc(sizeof(bf16_t) * 256 * 64);
    bf16_t* w4_lo = (bf16_t*)alloc(sizeof(bf16_t) * 256 * 64);

    hipMemsetAsync(cnt, 0, sizeof(int) * N, stream);
    hipMemsetAsync(fill, 0, sizeof(int) * N, stream);
    hipMemsetAsync(out, 0, sizeof(float) * out_size, stream);

    count_kernel<<<(E + 255) / 256, 256, 0, stream>>>(dst, cnt, E);
    int nb = (N + 255) / 256;   // 196
    scan_part<<<nb, 256, 0, stream>>>(cnt, bsum, pre, N);
    scan_bsum<<<1, 256, 0, stream>>>(bsum, nb);
    scan_final<<<nb, 256, 0, stream>>>(pre, bsum, cnt, row_ptr, dinv, N);
    fill_kernel<<<(E + 255) / 256, 256, 0, stream>>>(src, dst, row_ptr, fill, dinv, col, ew, E);
    graph_starts<<<nb, 256, 0, stream>>>(batch, gstart, N);
    prep_w_packed<256, 512><<<(256 * 512 + 255) / 256, 256, 0, stream>>>(W5, wt_hi, wt_lo);
    prep_w_packed<64, 256><<<(64 * 256 + 255) / 256, 256, 0, stream>>>(W4, w4_hi, w4_lo);

    // L1: transform-first (32 -> 8), then propagate (+b1, relu)
    transform_persist<32, 8, 32, false><<<1024, 256, 0, stream>>>(x, W1, nullptr, bufA, N);
    propagate_kernel<8, true><<<(N + 31) / 32, 256, 0, stream>>>(bufA, bufB, row_ptr, col, ew, dinv, b1, N);

    // L2: propagate-first (8), then transform 8->16
    propagate_kernel<8, false><<<(N + 31) / 32, 256, 0, stream>>>(bufB, bufA, row_ptr, col, ew, dinv, nullptr, N);
    transform_persist<8, 16, 32, true><<<1024, 256, 0, stream>>>(bufA, W2, b2, bufB, N);

    // L3: propagate (16), transform 16->64 with bf16 output
    propagate_kernel<16, false><<<(N + 15) / 16, 256, 0, stream>>>(bufB, bufA, row_ptr, col, ew, dinv, nullptr, N);
    bf16_t* h3b = (bf16_t*)bufB;
    transform_persist<16, 64, 16, true, float, bf16_t><<<1024, 256, 0, stream>>>(bufA, W3, b3, h3b, N);

    // L4: propagate bf16 (64), then MFMA transform 64->256 bf16->bf16
    bf16_t* h4a = (bf16_t*)bufA;
    propagate_kernel<64, false, bf16_t, bf16_t><<<(N + 3) / 4, 256, 0, stream>>>(h3b, h4a, row_ptr, col, ew, dinv, nullptr, N);
    bf16_t* h4b = (bf16_t*)bufB;
    transform4_mfma<<<(N + 63) / 64, 256, 0, stream>>>(h4a, w4_hi, w4_lo, b4, h4b, N);

    // L5: propagate bf16 (256), then MFMA GEMM + bias + relu + fused mean-pool
    bf16_t* h5in = (bf16_t*)bufA;
    propagate256_bf16<<<(N + 3) / 4, 256, 0, stream>>>(h4b, h5in, row_ptr, col, ew, dinv, N);
    gemm5_pool_mfma<<<(N + 63) / 64, 256, 0, stream>>>(h5in, wt_hi, wt_lo, b5, batch, out, N);
    divide_kernel<<<(NGRAPH * 512 + 255) / 256, 256, 0, stream>>>(out, gstart, NGRAPH * 512);
}